// Round 2
// baseline (959.328 us; speedup 1.0000x reference)
//
#include <hip/hip_runtime.h>

// ---------------------------------------------------------------------------
// SpGAT: x@W0+b0 -> 8x GAT heads (concat 512) -> GAT(512->64) -> softmax.
// CSR-by-src build per launch; bf16 MFMA GEMMs; bf16 intermediates.
// Heads processed in 2 halves of 4 to keep workspace <= ~195 MB.
// Edge weights recomputed in the aggregation kernel (no E*8 wcsr array).
// ---------------------------------------------------------------------------

using bf16x8 = __bf16 __attribute__((ext_vector_type(8)));
using f32x4  = float  __attribute__((ext_vector_type(4)));

__device__ __forceinline__ unsigned short f2bf(float f) {
    __bf16 h = (__bf16)f;                       // fptrunc, RNE
    return __builtin_bit_cast(unsigned short, h);
}
__device__ __forceinline__ float bfu2f(unsigned int u16) {  // low 16 bits = bf16
    return __builtin_bit_cast(float, u16 << 16);
}

#define ALPHA_NEG 0.2f

// ------------------------------ pack kernels -------------------------------
__global__ void pack_w0(const float* __restrict__ W0, unsigned short* __restrict__ W0t) {
    int idx = blockIdx.x * 256 + threadIdx.x;      // 16384
    int n = idx >> 7, k = idx & 127;
    W0t[n * 128 + k] = f2bf(W0[k * 128 + n]);
}
__global__ void pack_ball(const float* __restrict__ Wh, unsigned short* __restrict__ Bt) {
    int idx = blockIdx.x * 256 + threadIdx.x;      // 512*128 = 65536
    int c = idx >> 7, k = idx & 127;
    int h = c >> 6, f = c & 63;
    Bt[idx] = f2bf(Wh[(h * 128 + k) * 64 + f]);
}
__global__ void pack_wend(const float* __restrict__ We, unsigned short* __restrict__ Bt) {
    int idx = blockIdx.x * 256 + threadIdx.x;      // 64*512 = 32768
    int n = idx >> 9, k = idx & 511;
    Bt[idx] = f2bf(We[k * 64 + n]);
}

// ------------------------------- CSR build ---------------------------------
__global__ void edge_hist(const int* __restrict__ src, int* __restrict__ deg, int E) {
    int i = blockIdx.x * 256 + threadIdx.x;
    if (i < E) atomicAdd(&deg[src[i]], 1);
}

#define SCAN_BS 256
__global__ void scan_blocks(const int* __restrict__ deg, int* __restrict__ incl,
                            int* __restrict__ partials, int n) {
    __shared__ int s[SCAN_BS];
    int t = threadIdx.x, i = blockIdx.x * SCAN_BS + t;
    int v = (i < n) ? deg[i] : 0;
    s[t] = v; __syncthreads();
    for (int off = 1; off < SCAN_BS; off <<= 1) {
        int add = (t >= off) ? s[t - off] : 0;
        __syncthreads();
        s[t] += add;
        __syncthreads();
    }
    if (i < n) incl[i] = s[t];
    if (t == SCAN_BS - 1) partials[blockIdx.x] = s[t];
}
__global__ void scan_partials(int* __restrict__ partials, int nb) {  // 1 block, 512 thr
    __shared__ int s[512];
    int t = threadIdx.x;
    int v = (t < nb) ? partials[t] : 0;
    s[t] = v; __syncthreads();
    for (int off = 1; off < 512; off <<= 1) {
        int add = (t >= off) ? s[t - off] : 0;
        __syncthreads();
        s[t] += add;
        __syncthreads();
    }
    if (t < nb) partials[t] = s[t] - v;   // exclusive block offset
}
__global__ void finalize_rowptr(const int* __restrict__ deg, const int* __restrict__ incl,
                                const int* __restrict__ partials, int* __restrict__ row_ptr,
                                int* __restrict__ cursor, int n, int E) {
    int i = blockIdx.x * 256 + threadIdx.x;
    if (i < n) {
        int v = incl[i] - deg[i] + partials[i / SCAN_BS];
        row_ptr[i] = v;
        cursor[i] = v;
    } else if (i == n) {
        row_ptr[n] = E;
    }
}
__global__ void edge_scatter(const int* __restrict__ src, const int* __restrict__ dst,
                             int* __restrict__ cursor, int* __restrict__ dstp, int E) {
    int i = blockIdx.x * 256 + threadIdx.x;
    if (i < E) {
        int s = src[i];
        int p = atomicAdd(&cursor[s], 1);
        dstp[p] = dst[i];
    }
}

// ------------------------------- MFMA GEMM ---------------------------------
// C[M,NTOT] tile (BM x BN) = A[M,K] * Bt[NTOT,K]^T (+bias). bf16 in, fp32 acc.
// A/B frag [idx=lane&15][k=(lane>>4)*8+j]; C/D col=lane&15, row=(lane>>4)*4+reg.
template <int BM, int BN, int K, int WM, int WN, int MT, int NT, int NTOT,
          bool AF32, bool BIAS, bool OBF16>
__launch_bounds__(256)
__global__ void gemm_mfma(const void* __restrict__ Ap, const unsigned short* __restrict__ Bt,
                          const float* __restrict__ bias, void* __restrict__ Cp, int M) {
    constexpr int LDK = 40;                    // pad 32 -> 40 shorts (80B rows, 16B-aligned)
    __shared__ unsigned short As[BM * LDK];
    __shared__ unsigned short Bs[BN * LDK];
    const int t = threadIdx.x;
    const long m0 = (long)blockIdx.x * BM;
    const long n0 = (long)blockIdx.y * BN;
    const int wave = t >> 6, lane = t & 63;
    const int wm = wave / WN, wn = wave % WN;
    const int lrow = lane & 15, lq = lane >> 4;

    f32x4 acc[MT][NT];
#pragma unroll
    for (int a = 0; a < MT; a++)
#pragma unroll
        for (int b = 0; b < NT; b++) acc[a][b] = (f32x4)0.0f;

    for (int kt = 0; kt < K / 32; kt++) {
        const int k0 = kt * 32;
        if constexpr (AF32) {
            const float* A = (const float*)Ap;
#pragma unroll
            for (int it = 0; it < BM * 8 / 256; it++) {
                int L = t + 256 * it;
                int row = L >> 3, kc = (L & 7) * 4;
                long gr = m0 + row;
                float4 v = make_float4(0.f, 0.f, 0.f, 0.f);
                if (gr < M) v = *(const float4*)&A[gr * K + k0 + kc];
                unsigned int lo = (unsigned)f2bf(v.x) | ((unsigned)f2bf(v.y) << 16);
                unsigned int hi = (unsigned)f2bf(v.z) | ((unsigned)f2bf(v.w) << 16);
                *(uint2*)&As[row * LDK + kc] = make_uint2(lo, hi);
            }
        } else {
            const unsigned short* A = (const unsigned short*)Ap;
#pragma unroll
            for (int it = 0; it < BM * 4 / 256; it++) {
                int L = t + 256 * it;
                int row = L >> 2, kc = (L & 3) * 8;
                long gr = m0 + row;
                uint4 v = make_uint4(0u, 0u, 0u, 0u);
                if (gr < M) v = *(const uint4*)&A[gr * K + k0 + kc];
                *(uint4*)&As[row * LDK + kc] = v;
            }
        }
#pragma unroll
        for (int it = 0; it < BN * 4 / 256; it++) {
            int L = t + 256 * it;
            int row = L >> 2, kc = (L & 3) * 8;
            *(uint4*)&Bs[row * LDK + kc] = *(const uint4*)&Bt[(n0 + row) * K + k0 + kc];
        }
        __syncthreads();

        bf16x8 af[MT], bfr[NT];
#pragma unroll
        for (int mt = 0; mt < MT; mt++)
            af[mt] = *(const bf16x8*)&As[((wm * MT + mt) * 16 + lrow) * LDK + lq * 8];
#pragma unroll
        for (int nt = 0; nt < NT; nt++)
            bfr[nt] = *(const bf16x8*)&Bs[((wn * NT + nt) * 16 + lrow) * LDK + lq * 8];
#pragma unroll
        for (int mt = 0; mt < MT; mt++)
#pragma unroll
            for (int nt = 0; nt < NT; nt++)
                acc[mt][nt] = __builtin_amdgcn_mfma_f32_16x16x32_bf16(af[mt], bfr[nt],
                                                                     acc[mt][nt], 0, 0, 0);
        __syncthreads();
    }

#pragma unroll
    for (int mt = 0; mt < MT; mt++) {
        long rbase = m0 + (wm * MT + mt) * 16 + lq * 4;
#pragma unroll
        for (int nt = 0; nt < NT; nt++) {
            long col = n0 + (wn * NT + nt) * 16 + lrow;
            float bv = 0.f;
            if constexpr (BIAS) bv = bias[col];
#pragma unroll
            for (int r = 0; r < 4; r++) {
                long row = rbase + r;
                if (row < M) {
                    float v = acc[mt][nt][r] + bv;
                    if constexpr (OBF16)
                        ((unsigned short*)Cp)[row * NTOT + col] = f2bf(v);
                    else
                        ((float*)Cp)[row * NTOT + col] = v;
                }
            }
        }
    }
}

// ------------------- per-node scores for 4 heads of a half -----------------
// Hh [N,256] bf16. Writes ssrc/sdst at global head index half*4+m.
__global__ void head_scores_half(const unsigned short* __restrict__ Hh,
                                 const float* __restrict__ ah,
                                 float* __restrict__ ssrc, float* __restrict__ sdst,
                                 int half, int n) {
    int t = threadIdx.x, wave = t >> 6, lane = t & 63;
    int i = blockIdx.x * 4 + wave;
    if (i >= n) return;
    float rs[4], ds[4];
#pragma unroll
    for (int m = 0; m < 4; m++) {
        float v = bfu2f(Hh[(size_t)i * 256 + m * 64 + lane]);
        const float* am = ah + (half * 4 + m) * 128;
        rs[m] = v * am[lane];
        ds[m] = v * am[64 + lane];
    }
#pragma unroll
    for (int m = 0; m < 4; m++) {
        float a = rs[m], b = ds[m];
        for (int d = 32; d > 0; d >>= 1) {
            a += __shfl_xor(a, d, 64);
            b += __shfl_xor(b, d, 64);
        }
        rs[m] = a; ds[m] = b;
    }
    if (lane < 4) {
        float v = rs[0], w = ds[0];
#pragma unroll
        for (int m = 1; m < 4; m++)
            if (lane == m) { v = rs[m]; w = ds[m]; }
        ssrc[i * 8 + half * 4 + lane] = v;
        sdst[i * 8 + half * 4 + lane] = w;
    }
}

// ---------------- half aggregation (4 heads) + ELU, inline weights ---------
// Block (128 thr) per node; thread t covers cols 2t,2t+1 of the 256-wide half.
__global__ void agg_heads_half(const int* __restrict__ row_ptr, const int* __restrict__ dstp,
                               const float* __restrict__ ssrc, const float* __restrict__ sdst,
                               const unsigned short* __restrict__ Hh,
                               unsigned short* __restrict__ hcat, int half, int n) {
    __shared__ int jbuf[64];
    __shared__ float wbuf[256];
    __shared__ float ssh[4];
    __shared__ float rsh[4];
    int i = blockIdx.x, t = threadIdx.x;
    int e0 = row_ptr[i], e1 = row_ptr[i + 1];
    if (t < 4) ssh[t] = ssrc[i * 8 + half * 4 + t];
    int hl = t >> 5;                             // local head of col 2t
    float acc0 = 0.f, acc1 = 0.f, rs = 0.f;
    for (int base = e0; base < e1; base += 64) {
        int cnt = min(64, e1 - base);
        __syncthreads();                         // jbuf/wbuf reuse guard; ssh ready
        if (t < cnt) jbuf[t] = dstp[base + t];
        __syncthreads();
#pragma unroll
        for (int r = 0; r < 2; r++) {
            int ii = t + 128 * r;
            int q = ii >> 2, h = ii & 3;
            if (q < cnt) {
                int j = jbuf[q];
                float sc = ssh[h] + sdst[j * 8 + half * 4 + h];
                sc = sc > 0.f ? sc : ALPHA_NEG * sc;
                wbuf[ii] = __expf(-sc);
            }
        }
        __syncthreads();
        for (int q = 0; q < cnt; q++) {
            int j = jbuf[q];
            float w = wbuf[q * 4 + hl];
            unsigned int hv = *(const unsigned int*)&Hh[(size_t)j * 256 + 2 * t];
            acc0 += w * __builtin_bit_cast(float, hv << 16);
            acc1 += w * __builtin_bit_cast(float, hv & 0xffff0000u);
            if (t < 4) rs += wbuf[q * 4 + t];
        }
    }
    __syncthreads();
    if (t < 4) rsh[t] = rs;
    __syncthreads();
    float inv = 1.0f / (rsh[hl] + 1e-16f);
    float o0 = acc0 * inv, o1 = acc1 * inv;
    o0 = o0 > 0.f ? o0 : __expf(o0) - 1.0f;      // ELU
    o1 = o1 > 0.f ? o1 : __expf(o1) - 1.0f;
    unsigned int o = (unsigned)f2bf(o0) | ((unsigned)f2bf(o1) << 16);
    *(unsigned int*)&hcat[(size_t)i * 512 + half * 256 + 2 * t] = o;
}

// ----------------------------- final-layer scores --------------------------
__global__ void scores2(const float* __restrict__ h2, const float* __restrict__ ae,
                        float* __restrict__ ss2, float* __restrict__ sd2, int n) {
    int t = threadIdx.x, wave = t >> 6, lane = t & 63;
    int i = blockIdx.x * 4 + wave;
    if (i >= n) return;
    float v = h2[(size_t)i * 64 + lane];
    float a = v * ae[lane];
    float b = v * ae[64 + lane];
    for (int d = 32; d > 0; d >>= 1) {
        a += __shfl_xor(a, d, 64);
        b += __shfl_xor(b, d, 64);
    }
    if (lane == 0) { ss2[i] = a; sd2[i] = b; }
}

// --------------------- final aggregation + row softmax ---------------------
__global__ void agg_final(const int* __restrict__ row_ptr, const int* __restrict__ dstp,
                          const float* __restrict__ ss2, const float* __restrict__ sd2,
                          const float* __restrict__ h2, float* __restrict__ out, int n) {
    int t = threadIdx.x, wave = t >> 6, lane = t & 63;
    int i = blockIdx.x * 4 + wave;
    if (i >= n) return;
    int e0 = row_ptr[i], e1 = row_ptr[i + 1];
    float ssrc = ss2[i];
    float acc = 0.f, rs = 0.f;
    for (int p = e0; p < e1; p++) {
        int j = dstp[p];
        float sc = ssrc + sd2[j];
        sc = sc > 0.f ? sc : ALPHA_NEG * sc;
        float w = __expf(-sc);
        acc += w * h2[(size_t)j * 64 + lane];
        rs += w;
    }
    float o = acc / (rs + 1e-16f);
    float m = o;
    for (int d = 32; d > 0; d >>= 1) m = fmaxf(m, __shfl_xor(m, d, 64));
    float e = __expf(o - m);
    float s = e;
    for (int d = 32; d > 0; d >>= 1) s += __shfl_xor(s, d, 64);
    out[(size_t)i * 64 + lane] = e / s;
}

// ------------------------------- launcher ----------------------------------
extern "C" void kernel_launch(void* const* d_in, const int* in_sizes, int n_in,
                              void* d_out, int out_size, void* d_ws, size_t ws_size,
                              hipStream_t stream) {
    const float* x  = (const float*)d_in[0];
    const int* edges = (const int*)d_in[1];
    const float* W0 = (const float*)d_in[2];
    const float* b0 = (const float*)d_in[3];
    const float* Wh = (const float*)d_in[4];
    const float* ah = (const float*)d_in[5];
    const float* We = (const float*)d_in[6];
    const float* ae = (const float*)d_in[7];
    float* dout = (float*)d_out;

    const int Nn = in_sizes[0] / 128;   // 100000
    const int E  = in_sizes[1] / 2;     // 1600000
    const int* src = edges;
    const int* dst = edges + E;

    char* p = (char*)d_ws;
    auto alloc = [&](size_t bytes) -> char* {
        char* r = p;
        p += (bytes + 255) & ~(size_t)255;
        return r;
    };
    unsigned short* W0t   = (unsigned short*)alloc(128 * 128 * 2);
    unsigned short* Ballt = (unsigned short*)alloc(512 * 128 * 2);
    unsigned short* Wendt = (unsigned short*)alloc((size_t)64 * 512 * 2);
    int* deg     = (int*)alloc((size_t)Nn * 4);
    int* incl    = (int*)alloc((size_t)Nn * 4);
    int* part    = (int*)alloc(512 * 4);
    int* row_ptr = (int*)alloc((size_t)(Nn + 1) * 4);
    int* cursor  = (int*)alloc((size_t)Nn * 4);
    int* dstp    = (int*)alloc((size_t)E * 4);
    float* ssrc  = (float*)alloc((size_t)Nn * 8 * 4);
    float* sdst  = (float*)alloc((size_t)Nn * 8 * 4);
    float* ss2   = (float*)alloc((size_t)Nn * 4);
    float* sd2   = (float*)alloc((size_t)Nn * 4);
    unsigned short* xp = (unsigned short*)alloc((size_t)Nn * 128 * 2);
    unsigned short* Hh = (unsigned short*)alloc((size_t)Nn * 256 * 2);  // h2 aliases this
    unsigned short* hcat = (unsigned short*)alloc((size_t)Nn * 512 * 2);
    float* h2 = (float*)Hh;             // [N,64] fp32; Hh dead after last agg half

    size_t needed = (size_t)(p - (char*)d_ws);
    if (needed > ws_size) return;       // diagnostic: clean absmax-fail => ws too small

    const int gm = (Nn + 127) / 128;
    const int nScanB = (Nn + SCAN_BS - 1) / SCAN_BS;

    hipMemsetAsync(deg, 0, (size_t)Nn * 4, stream);
    pack_w0<<<64, 256, 0, stream>>>(W0, W0t);
    pack_ball<<<256, 256, 0, stream>>>(Wh, Ballt);
    pack_wend<<<128, 256, 0, stream>>>(We, Wendt);

    edge_hist<<<(E + 255) / 256, 256, 0, stream>>>(src, deg, E);
    scan_blocks<<<nScanB, 256, 0, stream>>>(deg, incl, part, Nn);
    scan_partials<<<1, 512, 0, stream>>>(part, nScanB);
    finalize_rowptr<<<(Nn + 256) / 256, 256, 0, stream>>>(deg, incl, part, row_ptr, cursor, Nn, E);
    edge_scatter<<<(E + 255) / 256, 256, 0, stream>>>(src, dst, cursor, dstp, E);

    // xp = bf16(x @ W0 + b0)
    gemm_mfma<128, 128, 128, 2, 2, 4, 4, 128, true, true, true>
        <<<dim3(gm, 1), 256, 0, stream>>>(x, W0t, b0, xp, Nn);

    for (int half = 0; half < 2; half++) {
        // Hh = bf16(xp @ W_half)  [N,256]
        gemm_mfma<128, 128, 128, 2, 2, 4, 4, 256, false, false, true>
            <<<dim3(gm, 2), 256, 0, stream>>>(xp, Ballt + (size_t)half * 256 * 128,
                                              nullptr, Hh, Nn);
        head_scores_half<<<(Nn + 3) / 4, 256, 0, stream>>>(Hh, ah, ssrc, sdst, half, Nn);
        agg_heads_half<<<Nn, 128, 0, stream>>>(row_ptr, dstp, ssrc, sdst, Hh, hcat, half, Nn);
    }

    // h2 = fp32(hcat @ W_end)  [N,64]   (h2 aliases Hh, which is now dead)
    gemm_mfma<128, 64, 512, 4, 1, 2, 4, 64, false, false, false>
        <<<dim3(gm, 1), 256, 0, stream>>>(hcat, Wendt, nullptr, h2, Nn);

    scores2<<<(Nn + 3) / 4, 256, 0, stream>>>(h2, ae, ss2, sd2, Nn);
    agg_final<<<(Nn + 3) / 4, 256, 0, stream>>>(row_ptr, dstp, ss2, sd2, h2, dout, Nn);
}

// Round 3
// 875.502 us; speedup vs baseline: 1.0957x; 1.0957x over previous
//
#include <hip/hip_runtime.h>

// ---------------------------------------------------------------------------
// SpGAT: x@W0+b0 -> 8x GAT heads (concat 512) -> GAT(512->64) -> softmax.
// CSR-by-src build per launch; bf16 MFMA GEMMs; bf16 intermediates.
// Heads in 2 halves of 4 (ws <= ~195 MB). Aggregation kernels: wave-per-node,
// no LDS/syncs, manual unroll for independent gather chains (R3).
// ---------------------------------------------------------------------------

using bf16x8 = __bf16 __attribute__((ext_vector_type(8)));
using f32x4  = float  __attribute__((ext_vector_type(4)));

__device__ __forceinline__ unsigned short f2bf(float f) {
    __bf16 h = (__bf16)f;                       // fptrunc, RNE
    return __builtin_bit_cast(unsigned short, h);
}
__device__ __forceinline__ float bflo(unsigned int u) {
    return __builtin_bit_cast(float, u << 16);
}
__device__ __forceinline__ float bfhi(unsigned int u) {
    return __builtin_bit_cast(float, u & 0xffff0000u);
}

#define ALPHA_NEG 0.2f

// ------------------------------ pack kernels -------------------------------
__global__ void pack_w0(const float* __restrict__ W0, unsigned short* __restrict__ W0t) {
    int idx = blockIdx.x * 256 + threadIdx.x;      // 16384
    int n = idx >> 7, k = idx & 127;
    W0t[n * 128 + k] = f2bf(W0[k * 128 + n]);
}
__global__ void pack_ball(const float* __restrict__ Wh, unsigned short* __restrict__ Bt) {
    int idx = blockIdx.x * 256 + threadIdx.x;      // 512*128 = 65536
    int c = idx >> 7, k = idx & 127;
    int h = c >> 6, f = c & 63;
    Bt[idx] = f2bf(Wh[(h * 128 + k) * 64 + f]);
}
__global__ void pack_wend(const float* __restrict__ We, unsigned short* __restrict__ Bt) {
    int idx = blockIdx.x * 256 + threadIdx.x;      // 64*512 = 32768
    int n = idx >> 9, k = idx & 511;
    Bt[idx] = f2bf(We[k * 64 + n]);
}

// ------------------------------- CSR build ---------------------------------
__global__ void edge_hist(const int* __restrict__ src, int* __restrict__ deg, int E) {
    int i = blockIdx.x * 256 + threadIdx.x;
    if (i < E) atomicAdd(&deg[src[i]], 1);
}

#define SCAN_BS 256
__global__ void scan_blocks(const int* __restrict__ deg, int* __restrict__ incl,
                            int* __restrict__ partials, int n) {
    __shared__ int s[SCAN_BS];
    int t = threadIdx.x, i = blockIdx.x * SCAN_BS + t;
    int v = (i < n) ? deg[i] : 0;
    s[t] = v; __syncthreads();
    for (int off = 1; off < SCAN_BS; off <<= 1) {
        int add = (t >= off) ? s[t - off] : 0;
        __syncthreads();
        s[t] += add;
        __syncthreads();
    }
    if (i < n) incl[i] = s[t];
    if (t == SCAN_BS - 1) partials[blockIdx.x] = s[t];
}
__global__ void scan_partials(int* __restrict__ partials, int nb) {  // 1 block, 512 thr
    __shared__ int s[512];
    int t = threadIdx.x;
    int v = (t < nb) ? partials[t] : 0;
    s[t] = v; __syncthreads();
    for (int off = 1; off < 512; off <<= 1) {
        int add = (t >= off) ? s[t - off] : 0;
        __syncthreads();
        s[t] += add;
        __syncthreads();
    }
    if (t < nb) partials[t] = s[t] - v;   // exclusive block offset
}
__global__ void finalize_rowptr(const int* __restrict__ deg, const int* __restrict__ incl,
                                const int* __restrict__ partials, int* __restrict__ row_ptr,
                                int* __restrict__ cursor, int n, int E) {
    int i = blockIdx.x * 256 + threadIdx.x;
    if (i < n) {
        int v = incl[i] - deg[i] + partials[i / SCAN_BS];
        row_ptr[i] = v;
        cursor[i] = v;
    } else if (i == n) {
        row_ptr[n] = E;
    }
}
__global__ void edge_scatter(const int* __restrict__ src, const int* __restrict__ dst,
                             int* __restrict__ cursor, int* __restrict__ dstp, int E) {
    int i = blockIdx.x * 256 + threadIdx.x;
    if (i < E) {
        int s = src[i];
        int p = atomicAdd(&cursor[s], 1);
        dstp[p] = dst[i];
    }
}

// ------------------------------- MFMA GEMM ---------------------------------
// C[M,NTOT] tile (BM x BN) = A[M,K] * Bt[NTOT,K]^T (+bias). bf16 in, fp32 acc.
// A/B frag [idx=lane&15][k=(lane>>4)*8+j]; C/D col=lane&15, row=(lane>>4)*4+reg.
template <int BM, int BN, int K, int WM, int WN, int MT, int NT, int NTOT,
          bool AF32, bool BIAS, bool OBF16>
__launch_bounds__(256)
__global__ void gemm_mfma(const void* __restrict__ Ap, const unsigned short* __restrict__ Bt,
                          const float* __restrict__ bias, void* __restrict__ Cp, int M) {
    constexpr int LDK = 40;                    // pad 32 -> 40 shorts (80B rows, 16B-aligned)
    __shared__ unsigned short As[BM * LDK];
    __shared__ unsigned short Bs[BN * LDK];
    const int t = threadIdx.x;
    const long m0 = (long)blockIdx.x * BM;
    const long n0 = (long)blockIdx.y * BN;
    const int wave = t >> 6, lane = t & 63;
    const int wm = wave / WN, wn = wave % WN;
    const int lrow = lane & 15, lq = lane >> 4;

    f32x4 acc[MT][NT];
#pragma unroll
    for (int a = 0; a < MT; a++)
#pragma unroll
        for (int b = 0; b < NT; b++) acc[a][b] = (f32x4)0.0f;

    for (int kt = 0; kt < K / 32; kt++) {
        const int k0 = kt * 32;
        if constexpr (AF32) {
            const float* A = (const float*)Ap;
#pragma unroll
            for (int it = 0; it < BM * 8 / 256; it++) {
                int L = t + 256 * it;
                int row = L >> 3, kc = (L & 7) * 4;
                long gr = m0 + row;
                float4 v = make_float4(0.f, 0.f, 0.f, 0.f);
                if (gr < M) v = *(const float4*)&A[gr * K + k0 + kc];
                unsigned int lo = (unsigned)f2bf(v.x) | ((unsigned)f2bf(v.y) << 16);
                unsigned int hi = (unsigned)f2bf(v.z) | ((unsigned)f2bf(v.w) << 16);
                *(uint2*)&As[row * LDK + kc] = make_uint2(lo, hi);
            }
        } else {
            const unsigned short* A = (const unsigned short*)Ap;
#pragma unroll
            for (int it = 0; it < BM * 4 / 256; it++) {
                int L = t + 256 * it;
                int row = L >> 2, kc = (L & 3) * 8;
                long gr = m0 + row;
                uint4 v = make_uint4(0u, 0u, 0u, 0u);
                if (gr < M) v = *(const uint4*)&A[gr * K + k0 + kc];
                *(uint4*)&As[row * LDK + kc] = v;
            }
        }
#pragma unroll
        for (int it = 0; it < BN * 4 / 256; it++) {
            int L = t + 256 * it;
            int row = L >> 2, kc = (L & 3) * 8;
            *(uint4*)&Bs[row * LDK + kc] = *(const uint4*)&Bt[(n0 + row) * K + k0 + kc];
        }
        __syncthreads();

        bf16x8 af[MT], bfr[NT];
#pragma unroll
        for (int mt = 0; mt < MT; mt++)
            af[mt] = *(const bf16x8*)&As[((wm * MT + mt) * 16 + lrow) * LDK + lq * 8];
#pragma unroll
        for (int nt = 0; nt < NT; nt++)
            bfr[nt] = *(const bf16x8*)&Bs[((wn * NT + nt) * 16 + lrow) * LDK + lq * 8];
#pragma unroll
        for (int mt = 0; mt < MT; mt++)
#pragma unroll
            for (int nt = 0; nt < NT; nt++)
                acc[mt][nt] = __builtin_amdgcn_mfma_f32_16x16x32_bf16(af[mt], bfr[nt],
                                                                     acc[mt][nt], 0, 0, 0);
        __syncthreads();
    }

#pragma unroll
    for (int mt = 0; mt < MT; mt++) {
        long rbase = m0 + (wm * MT + mt) * 16 + lq * 4;
#pragma unroll
        for (int nt = 0; nt < NT; nt++) {
            long col = n0 + (wn * NT + nt) * 16 + lrow;
            float bv = 0.f;
            if constexpr (BIAS) bv = bias[col];
#pragma unroll
            for (int r = 0; r < 4; r++) {
                long row = rbase + r;
                if (row < M) {
                    float v = acc[mt][nt][r] + bv;
                    if constexpr (OBF16)
                        ((unsigned short*)Cp)[row * NTOT + col] = f2bf(v);
                    else
                        ((float*)Cp)[row * NTOT + col] = v;
                }
            }
        }
    }
}

// ------------------- per-node scores for 4 heads of a half -----------------
__global__ void head_scores_half(const unsigned short* __restrict__ Hh,
                                 const float* __restrict__ ah,
                                 float* __restrict__ ssrc, float* __restrict__ sdst,
                                 int half, int n) {
    int t = threadIdx.x, wave = t >> 6, lane = t & 63;
    int i = blockIdx.x * 4 + wave;
    if (i >= n) return;
    float rs[4], ds[4];
#pragma unroll
    for (int m = 0; m < 4; m++) {
        float v = bflo(Hh[(size_t)i * 256 + m * 64 + lane]);
        const float* am = ah + (half * 4 + m) * 128;
        rs[m] = v * am[lane];
        ds[m] = v * am[64 + lane];
    }
#pragma unroll
    for (int m = 0; m < 4; m++) {
        float a = rs[m], b = ds[m];
        for (int d = 32; d > 0; d >>= 1) {
            a += __shfl_xor(a, d, 64);
            b += __shfl_xor(b, d, 64);
        }
        rs[m] = a; ds[m] = b;
    }
    if (lane < 4) {
        float v = rs[0], w = ds[0];
#pragma unroll
        for (int m = 1; m < 4; m++)
            if (lane == m) { v = rs[m]; w = ds[m]; }
        ssrc[i * 8 + half * 4 + lane] = v;
        sdst[i * 8 + half * 4 + lane] = w;
    }
}

// ---------------- half aggregation (4 heads) + ELU ------------------------
// Wave per node. Lane owns 4 cols of the 256-wide half (uint2 = 8B/edge).
// Head weight computed redundantly per 16-lane group (no LDS, no syncs).
__global__ void agg_heads_half(const int* __restrict__ row_ptr, const int* __restrict__ dstp,
                               const float* __restrict__ ssrc, const float* __restrict__ sdst,
                               const unsigned short* __restrict__ Hh,
                               unsigned short* __restrict__ hcat, int half, int n) {
    int t = threadIdx.x, wave = t >> 6, lane = t & 63;
    int i = blockIdx.x * 4 + wave;
    if (i >= n) return;
    int e0 = row_ptr[i], e1 = row_ptr[i + 1];
    int h = lane >> 4;                           // local head of cols 4*lane..+3
    float ss = ssrc[i * 8 + half * 4 + h];
    const float* sdh = sdst + half * 4 + h;
    float a0 = 0.f, a1 = 0.f, a2 = 0.f, a3 = 0.f, rs = 0.f;
    int p = e0;
    for (; p + 2 <= e1; p += 2) {
        int j0 = dstp[p], j1 = dstp[p + 1];
        float sd0 = sdh[(size_t)j0 * 8], sd1 = sdh[(size_t)j1 * 8];
        uint2 hv0 = *(const uint2*)&Hh[(size_t)j0 * 256 + lane * 4];
        uint2 hv1 = *(const uint2*)&Hh[(size_t)j1 * 256 + lane * 4];
        float sc0 = ss + sd0; sc0 = sc0 > 0.f ? sc0 : ALPHA_NEG * sc0;
        float sc1 = ss + sd1; sc1 = sc1 > 0.f ? sc1 : ALPHA_NEG * sc1;
        float w0 = __expf(-sc0), w1 = __expf(-sc1);
        rs += w0 + w1;
        a0 += w0 * bflo(hv0.x) + w1 * bflo(hv1.x);
        a1 += w0 * bfhi(hv0.x) + w1 * bfhi(hv1.x);
        a2 += w0 * bflo(hv0.y) + w1 * bflo(hv1.y);
        a3 += w0 * bfhi(hv0.y) + w1 * bfhi(hv1.y);
    }
    if (p < e1) {
        int j0 = dstp[p];
        float sd0 = sdh[(size_t)j0 * 8];
        uint2 hv0 = *(const uint2*)&Hh[(size_t)j0 * 256 + lane * 4];
        float sc0 = ss + sd0; sc0 = sc0 > 0.f ? sc0 : ALPHA_NEG * sc0;
        float w0 = __expf(-sc0);
        rs += w0;
        a0 += w0 * bflo(hv0.x);
        a1 += w0 * bfhi(hv0.x);
        a2 += w0 * bflo(hv0.y);
        a3 += w0 * bfhi(hv0.y);
    }
    float inv = 1.0f / (rs + 1e-16f);
    float o0 = a0 * inv, o1 = a1 * inv, o2 = a2 * inv, o3 = a3 * inv;
    o0 = o0 > 0.f ? o0 : __expf(o0) - 1.0f;      // ELU
    o1 = o1 > 0.f ? o1 : __expf(o1) - 1.0f;
    o2 = o2 > 0.f ? o2 : __expf(o2) - 1.0f;
    o3 = o3 > 0.f ? o3 : __expf(o3) - 1.0f;
    uint2 o = make_uint2((unsigned)f2bf(o0) | ((unsigned)f2bf(o1) << 16),
                         (unsigned)f2bf(o2) | ((unsigned)f2bf(o3) << 16));
    *(uint2*)&hcat[(size_t)i * 512 + half * 256 + lane * 4] = o;
}

// ----------------------------- final-layer scores --------------------------
__global__ void scores2(const float* __restrict__ h2, const float* __restrict__ ae,
                        float* __restrict__ ss2, float* __restrict__ sd2, int n) {
    int t = threadIdx.x, wave = t >> 6, lane = t & 63;
    int i = blockIdx.x * 4 + wave;
    if (i >= n) return;
    float v = h2[(size_t)i * 64 + lane];
    float a = v * ae[lane];
    float b = v * ae[64 + lane];
    for (int d = 32; d > 0; d >>= 1) {
        a += __shfl_xor(a, d, 64);
        b += __shfl_xor(b, d, 64);
    }
    if (lane == 0) { ss2[i] = a; sd2[i] = b; }
}

// --------------------- final aggregation + row softmax ---------------------
// Wave per node, lane = col; 4-way unrolled independent gather chains.
__global__ void agg_final(const int* __restrict__ row_ptr, const int* __restrict__ dstp,
                          const float* __restrict__ ss2, const float* __restrict__ sd2,
                          const float* __restrict__ h2, float* __restrict__ out, int n) {
    int t = threadIdx.x, wave = t >> 6, lane = t & 63;
    int i = blockIdx.x * 4 + wave;
    if (i >= n) return;
    int e0 = row_ptr[i], e1 = row_ptr[i + 1];
    float ssrc = ss2[i];
    float acc = 0.f, rs = 0.f;
    int p = e0;
    for (; p + 4 <= e1; p += 4) {
        int j0 = dstp[p], j1 = dstp[p + 1], j2 = dstp[p + 2], j3 = dstp[p + 3];
        float s0 = ssrc + sd2[j0], s1 = ssrc + sd2[j1];
        float s2 = ssrc + sd2[j2], s3 = ssrc + sd2[j3];
        float v0 = h2[(size_t)j0 * 64 + lane], v1 = h2[(size_t)j1 * 64 + lane];
        float v2 = h2[(size_t)j2 * 64 + lane], v3 = h2[(size_t)j3 * 64 + lane];
        s0 = s0 > 0.f ? s0 : ALPHA_NEG * s0;
        s1 = s1 > 0.f ? s1 : ALPHA_NEG * s1;
        s2 = s2 > 0.f ? s2 : ALPHA_NEG * s2;
        s3 = s3 > 0.f ? s3 : ALPHA_NEG * s3;
        float w0 = __expf(-s0), w1 = __expf(-s1), w2 = __expf(-s2), w3 = __expf(-s3);
        rs += (w0 + w1) + (w2 + w3);
        acc += w0 * v0 + w1 * v1 + w2 * v2 + w3 * v3;
    }
    for (; p < e1; p++) {
        int j = dstp[p];
        float sc = ssrc + sd2[j];
        sc = sc > 0.f ? sc : ALPHA_NEG * sc;
        float w = __expf(-sc);
        acc += w * h2[(size_t)j * 64 + lane];
        rs += w;
    }
    float o = acc / (rs + 1e-16f);
    float m = o;
    for (int d = 32; d > 0; d >>= 1) m = fmaxf(m, __shfl_xor(m, d, 64));
    float e = __expf(o - m);
    float s = e;
    for (int d = 32; d > 0; d >>= 1) s += __shfl_xor(s, d, 64);
    out[(size_t)i * 64 + lane] = e / s;
}

// ------------------------------- launcher ----------------------------------
extern "C" void kernel_launch(void* const* d_in, const int* in_sizes, int n_in,
                              void* d_out, int out_size, void* d_ws, size_t ws_size,
                              hipStream_t stream) {
    const float* x  = (const float*)d_in[0];
    const int* edges = (const int*)d_in[1];
    const float* W0 = (const float*)d_in[2];
    const float* b0 = (const float*)d_in[3];
    const float* Wh = (const float*)d_in[4];
    const float* ah = (const float*)d_in[5];
    const float* We = (const float*)d_in[6];
    const float* ae = (const float*)d_in[7];
    float* dout = (float*)d_out;

    const int Nn = in_sizes[0] / 128;   // 100000
    const int E  = in_sizes[1] / 2;     // 1600000
    const int* src = edges;
    const int* dst = edges + E;

    char* p = (char*)d_ws;
    auto alloc = [&](size_t bytes) -> char* {
        char* r = p;
        p += (bytes + 255) & ~(size_t)255;
        return r;
    };
    unsigned short* W0t   = (unsigned short*)alloc(128 * 128 * 2);
    unsigned short* Ballt = (unsigned short*)alloc(512 * 128 * 2);
    unsigned short* Wendt = (unsigned short*)alloc((size_t)64 * 512 * 2);
    int* deg     = (int*)alloc((size_t)Nn * 4);
    int* incl    = (int*)alloc((size_t)Nn * 4);
    int* part    = (int*)alloc(512 * 4);
    int* row_ptr = (int*)alloc((size_t)(Nn + 1) * 4);
    int* cursor  = (int*)alloc((size_t)Nn * 4);
    int* dstp    = (int*)alloc((size_t)E * 4);
    float* ssrc  = (float*)alloc((size_t)Nn * 8 * 4);
    float* sdst  = (float*)alloc((size_t)Nn * 8 * 4);
    float* ss2   = (float*)alloc((size_t)Nn * 4);
    float* sd2   = (float*)alloc((size_t)Nn * 4);
    unsigned short* xp = (unsigned short*)alloc((size_t)Nn * 128 * 2);
    unsigned short* Hh = (unsigned short*)alloc((size_t)Nn * 256 * 2);  // h2 aliases this
    unsigned short* hcat = (unsigned short*)alloc((size_t)Nn * 512 * 2);
    float* h2 = (float*)Hh;             // [N,64] fp32; Hh dead after last agg half

    size_t needed = (size_t)(p - (char*)d_ws);
    if (needed > ws_size) return;       // diagnostic: clean absmax-fail => ws too small

    const int gm = (Nn + 127) / 128;
    const int nScanB = (Nn + SCAN_BS - 1) / SCAN_BS;

    hipMemsetAsync(deg, 0, (size_t)Nn * 4, stream);
    pack_w0<<<64, 256, 0, stream>>>(W0, W0t);
    pack_ball<<<256, 256, 0, stream>>>(Wh, Ballt);
    pack_wend<<<128, 256, 0, stream>>>(We, Wendt);

    edge_hist<<<(E + 255) / 256, 256, 0, stream>>>(src, deg, E);
    scan_blocks<<<nScanB, 256, 0, stream>>>(deg, incl, part, Nn);
    scan_partials<<<1, 512, 0, stream>>>(part, nScanB);
    finalize_rowptr<<<(Nn + 256) / 256, 256, 0, stream>>>(deg, incl, part, row_ptr, cursor, Nn, E);
    edge_scatter<<<(E + 255) / 256, 256, 0, stream>>>(src, dst, cursor, dstp, E);

    // xp = bf16(x @ W0 + b0)
    gemm_mfma<128, 128, 128, 2, 2, 4, 4, 128, true, true, true>
        <<<dim3(gm, 1), 256, 0, stream>>>(x, W0t, b0, xp, Nn);

    for (int half = 0; half < 2; half++) {
        // Hh = bf16(xp @ W_half)  [N,256]
        gemm_mfma<128, 128, 128, 2, 2, 4, 4, 256, false, false, true>
            <<<dim3(gm, 2), 256, 0, stream>>>(xp, Ballt + (size_t)half * 256 * 128,
                                              nullptr, Hh, Nn);
        head_scores_half<<<(Nn + 3) / 4, 256, 0, stream>>>(Hh, ah, ssrc, sdst, half, Nn);
        agg_heads_half<<<(Nn + 3) / 4, 256, 0, stream>>>(row_ptr, dstp, ssrc, sdst, Hh,
                                                         hcat, half, Nn);
    }

    // h2 = fp32(hcat @ W_end)  [N,64]   (h2 aliases Hh, which is now dead)
    gemm_mfma<128, 64, 512, 4, 1, 2, 4, 64, false, false, false>
        <<<dim3(gm, 1), 256, 0, stream>>>(hcat, Wendt, nullptr, h2, Nn);

    scores2<<<(Nn + 3) / 4, 256, 0, stream>>>(h2, ae, ss2, sd2, Nn);
    agg_final<<<(Nn + 3) / 4, 256, 0, stream>>>(row_ptr, dstp, ss2, sd2, h2, dout, Nn);
}

// Round 4
// 865.924 us; speedup vs baseline: 1.1079x; 1.0111x over previous
//
#include <hip/hip_runtime.h>

// ---------------------------------------------------------------------------
// SpGAT: x@W0+b0 -> 8x GAT heads (concat 512) -> GAT(512->64) -> softmax.
// R4: aggregate xp (256 B/edge, once for all 8 heads) instead of H (1 KB/edge):
//   z[i,h,:] = (sum_e w_e^h xp[dst_e]) / rowsum_h   (fp32 regs -> bf16, chunked)
//   hcat[i, h*64:+64] = ELU(z_h @ W_h)              (batched MFMA GEMM, grid.z=8)
// Head scores via precomputed w~ = W_h @ a parts: s = xp . w~  (no H at all).
// ---------------------------------------------------------------------------

using bf16x8 = __bf16 __attribute__((ext_vector_type(8)));
using f32x4  = float  __attribute__((ext_vector_type(4)));

__device__ __forceinline__ unsigned short f2bf(float f) {
    __bf16 h = (__bf16)f;                       // fptrunc, RNE
    return __builtin_bit_cast(unsigned short, h);
}
__device__ __forceinline__ float bflo(unsigned int u) {
    return __builtin_bit_cast(float, u << 16);
}
__device__ __forceinline__ float bfhi(unsigned int u) {
    return __builtin_bit_cast(float, u & 0xffff0000u);
}

#define ALPHA_NEG 0.2f
#define CHUNK 12800

// ------------------------------ pack kernels -------------------------------
__global__ void pack_w0(const float* __restrict__ W0, unsigned short* __restrict__ W0t) {
    int idx = blockIdx.x * 256 + threadIdx.x;      // 16384
    int n = idx >> 7, k = idx & 127;
    W0t[n * 128 + k] = f2bf(W0[k * 128 + n]);
}
// W_heads [8][128k][64f] fp32 -> Ballt [h][f][k] bf16  (= per-head B^T)
__global__ void pack_ball(const float* __restrict__ Wh, unsigned short* __restrict__ Bt) {
    int idx = blockIdx.x * 256 + threadIdx.x;      // 65536
    int c = idx >> 7, k = idx & 127;
    int h = c >> 6, f = c & 63;
    Bt[idx] = f2bf(Wh[(h * 128 + k) * 64 + f]);
}
__global__ void pack_wend(const float* __restrict__ We, unsigned short* __restrict__ Bt) {
    int idx = blockIdx.x * 256 + threadIdx.x;      // 32768
    int n = idx >> 9, k = idx & 511;
    Bt[idx] = f2bf(We[k * 64 + n]);
}
// w~_src[h][k] = sum_f W_h[k][f]*a_h[f];  w~_dst with a_h[64+f]
__global__ void pack_wa(const float* __restrict__ Wh, const float* __restrict__ ah,
                        float* __restrict__ was, float* __restrict__ wad) {
    int idx = blockIdx.x * 256 + threadIdx.x;      // 1024
    if (idx >= 1024) return;
    int h = idx >> 7, k = idx & 127;
    float s = 0.f, d = 0.f;
    for (int f = 0; f < 64; f++) {
        float wv = Wh[(h * 128 + k) * 64 + f];
        s += wv * ah[h * 128 + f];
        d += wv * ah[h * 128 + 64 + f];
    }
    was[idx] = s;
    wad[idx] = d;
}

// ------------------------------- CSR build ---------------------------------
__global__ void edge_hist(const int* __restrict__ src, int* __restrict__ deg, int E) {
    int i = blockIdx.x * 256 + threadIdx.x;
    if (i < E) atomicAdd(&deg[src[i]], 1);
}

#define SCAN_BS 256
__global__ void scan_blocks(const int* __restrict__ deg, int* __restrict__ incl,
                            int* __restrict__ partials, int n) {
    __shared__ int s[SCAN_BS];
    int t = threadIdx.x, i = blockIdx.x * SCAN_BS + t;
    int v = (i < n) ? deg[i] : 0;
    s[t] = v; __syncthreads();
    for (int off = 1; off < SCAN_BS; off <<= 1) {
        int add = (t >= off) ? s[t - off] : 0;
        __syncthreads();
        s[t] += add;
        __syncthreads();
    }
    if (i < n) incl[i] = s[t];
    if (t == SCAN_BS - 1) partials[blockIdx.x] = s[t];
}
__global__ void scan_partials(int* __restrict__ partials, int nb) {  // 1 block, 512 thr
    __shared__ int s[512];
    int t = threadIdx.x;
    int v = (t < nb) ? partials[t] : 0;
    s[t] = v; __syncthreads();
    for (int off = 1; off < 512; off <<= 1) {
        int add = (t >= off) ? s[t - off] : 0;
        __syncthreads();
        s[t] += add;
        __syncthreads();
    }
    if (t < nb) partials[t] = s[t] - v;   // exclusive block offset
}
__global__ void finalize_rowptr(const int* __restrict__ deg, const int* __restrict__ incl,
                                const int* __restrict__ partials, int* __restrict__ row_ptr,
                                int* __restrict__ cursor, int n, int E) {
    int i = blockIdx.x * 256 + threadIdx.x;
    if (i < n) {
        int v = incl[i] - deg[i] + partials[i / SCAN_BS];
        row_ptr[i] = v;
        cursor[i] = v;
    } else if (i == n) {
        row_ptr[n] = E;
    }
}
__global__ void edge_scatter(const int* __restrict__ src, const int* __restrict__ dst,
                             int* __restrict__ cursor, int* __restrict__ dstp, int E) {
    int i = blockIdx.x * 256 + threadIdx.x;
    if (i < E) {
        int s = src[i];
        int p = atomicAdd(&cursor[s], 1);
        dstp[p] = dst[i];
    }
}

// ------------------------------- MFMA GEMM ---------------------------------
// C tile (BM x BN) = A[M,(lda)] * Bt[.,K]^T (+bias, opt ELU). bf16 in, fp32 acc.
// BATCHZ: blockIdx.z = head; A col offset z*K, B ptr offset z*BN*K, C col offset z*BN.
// A/B frag [idx=lane&15][k=(lane>>4)*8+j]; C/D col=lane&15, row=(lane>>4)*4+reg.
template <int BM, int BN, int K, int WM, int WN, int MT, int NT,
          bool AF32, bool BIAS, bool OBF16, bool ELU, bool BATCHZ>
__launch_bounds__(256)
__global__ void gemm_mfma(const void* __restrict__ Ap, const unsigned short* __restrict__ Bt,
                          const float* __restrict__ bias, void* __restrict__ Cp, int M,
                          int lda, int ldc) {
    constexpr int LDK = 40;                    // pad 32 -> 40 shorts (80B rows, 16B-aligned)
    __shared__ unsigned short As[BM * LDK];
    __shared__ unsigned short Bs[BN * LDK];
    const int t = threadIdx.x;
    const long m0 = (long)blockIdx.x * BM;
    const long n0 = (long)blockIdx.y * BN;
    const int abase = BATCHZ ? blockIdx.z * K : 0;
    const unsigned short* Btz = BATCHZ ? Bt + (size_t)blockIdx.z * BN * K : Bt;
    const long cbase = BATCHZ ? (long)blockIdx.z * BN : 0;
    const int wave = t >> 6, lane = t & 63;
    const int wm = wave / WN, wn = wave % WN;
    const int lrow = lane & 15, lq = lane >> 4;

    f32x4 acc[MT][NT];
#pragma unroll
    for (int a = 0; a < MT; a++)
#pragma unroll
        for (int b = 0; b < NT; b++) acc[a][b] = (f32x4)0.0f;

    for (int kt = 0; kt < K / 32; kt++) {
        const int k0 = kt * 32;
        if constexpr (AF32) {
            const float* A = (const float*)Ap;
#pragma unroll
            for (int it = 0; it < BM * 8 / 256; it++) {
                int L = t + 256 * it;
                int row = L >> 3, kc = (L & 7) * 4;
                long gr = m0 + row;
                float4 v = make_float4(0.f, 0.f, 0.f, 0.f);
                if (gr < M) v = *(const float4*)&A[gr * lda + abase + k0 + kc];
                unsigned int lo = (unsigned)f2bf(v.x) | ((unsigned)f2bf(v.y) << 16);
                unsigned int hi = (unsigned)f2bf(v.z) | ((unsigned)f2bf(v.w) << 16);
                *(uint2*)&As[row * LDK + kc] = make_uint2(lo, hi);
            }
        } else {
            const unsigned short* A = (const unsigned short*)Ap;
#pragma unroll
            for (int it = 0; it < BM * 4 / 256; it++) {
                int L = t + 256 * it;
                int row = L >> 2, kc = (L & 3) * 8;
                long gr = m0 + row;
                uint4 v = make_uint4(0u, 0u, 0u, 0u);
                if (gr < M) v = *(const uint4*)&A[gr * lda + abase + k0 + kc];
                *(uint4*)&As[row * LDK + kc] = v;
            }
        }
#pragma unroll
        for (int it = 0; it < BN * 4 / 256; it++) {
            int L = t + 256 * it;
            int row = L >> 2, kc = (L & 3) * 8;
            *(uint4*)&Bs[row * LDK + kc] = *(const uint4*)&Btz[(n0 + row) * K + k0 + kc];
        }
        __syncthreads();

        bf16x8 af[MT], bfr[NT];
#pragma unroll
        for (int mt = 0; mt < MT; mt++)
            af[mt] = *(const bf16x8*)&As[((wm * MT + mt) * 16 + lrow) * LDK + lq * 8];
#pragma unroll
        for (int nt = 0; nt < NT; nt++)
            bfr[nt] = *(const bf16x8*)&Bs[((wn * NT + nt) * 16 + lrow) * LDK + lq * 8];
#pragma unroll
        for (int mt = 0; mt < MT; mt++)
#pragma unroll
            for (int nt = 0; nt < NT; nt++)
                acc[mt][nt] = __builtin_amdgcn_mfma_f32_16x16x32_bf16(af[mt], bfr[nt],
                                                                     acc[mt][nt], 0, 0, 0);
        __syncthreads();
    }

#pragma unroll
    for (int mt = 0; mt < MT; mt++) {
        long rbase = m0 + (wm * MT + mt) * 16 + lq * 4;
#pragma unroll
        for (int nt = 0; nt < NT; nt++) {
            long col = cbase + n0 + (wn * NT + nt) * 16 + lrow;
            float bv = 0.f;
            if constexpr (BIAS) bv = bias[col];
#pragma unroll
            for (int r = 0; r < 4; r++) {
                long row = rbase + r;
                if (row < M) {
                    float v = acc[mt][nt][r] + bv;
                    if constexpr (ELU) v = v > 0.f ? v : __expf(v) - 1.0f;
                    if constexpr (OBF16)
                        ((unsigned short*)Cp)[row * ldc + col] = f2bf(v);
                    else
                        ((float*)Cp)[row * ldc + col] = v;
                }
            }
        }
    }
}

// ---------------- per-node per-head scores from xp and w~ ------------------
// s_src[i,h] = xp[i,:] . was[h,:]  (wave per node; lane owns cols 2l,2l+1)
__global__ void scores_xp(const unsigned short* __restrict__ xp,
                          const float* __restrict__ was, const float* __restrict__ wad,
                          float* __restrict__ ssrc, float* __restrict__ sdst, int n) {
    int t = threadIdx.x, wave = t >> 6, lane = t & 63;
    int i = blockIdx.x * 4 + wave;
    if (i >= n) return;
    unsigned xv = *(const unsigned*)&xp[(size_t)i * 128 + 2 * lane];
    float x0 = bflo(xv), x1 = bfhi(xv);
    float sa[8], sb[8];
#pragma unroll
    for (int h = 0; h < 8; h++) {
        sa[h] = x0 * was[h * 128 + 2 * lane] + x1 * was[h * 128 + 2 * lane + 1];
        sb[h] = x0 * wad[h * 128 + 2 * lane] + x1 * wad[h * 128 + 2 * lane + 1];
    }
#pragma unroll
    for (int h = 0; h < 8; h++) {
        float a = sa[h], b = sb[h];
        for (int d = 32; d > 0; d >>= 1) {
            a += __shfl_xor(a, d, 64);
            b += __shfl_xor(b, d, 64);
        }
        sa[h] = a; sb[h] = b;
    }
    if (lane < 8) {
        float v = sa[0], w = sb[0];
#pragma unroll
        for (int h = 1; h < 8; h++)
            if (lane == h) { v = sa[h]; w = sb[h]; }
        ssrc[i * 8 + lane] = v;
        sdst[i * 8 + lane] = w;
    }
}

// ---------------- 8-head xp aggregation (chunked), zero shuffles -----------
// Wave per node. lane: head h=lane>>3, sub=lane&7 -> owns xp cols sub*16..+15.
// All 8 lanes of a head compute the same weight (redundant exp, no cross-lane).
__global__ void agg_xp(const int* __restrict__ row_ptr, const int* __restrict__ dstp,
                       const float* __restrict__ ssrc, const float* __restrict__ sdst,
                       const unsigned short* __restrict__ xp, unsigned short* __restrict__ z,
                       int n0, int n1) {
    int t = threadIdx.x, wave = t >> 6, lane = t & 63;
    int i = n0 + blockIdx.x * 4 + wave;
    if (i >= n1) return;
    int e0 = row_ptr[i], e1 = row_ptr[i + 1];
    int h = lane >> 3, sub = lane & 7;
    float ssv = ssrc[i * 8 + h];
    float acc[16];
#pragma unroll
    for (int c = 0; c < 16; c++) acc[c] = 0.f;
    float rs = 0.f;
    int p = e0;
    for (; p + 2 <= e1; p += 2) {
        int j0 = dstp[p], j1 = dstp[p + 1];
        float s0 = ssv + sdst[(size_t)j0 * 8 + h];
        float s1 = ssv + sdst[(size_t)j1 * 8 + h];
        uint4 xa0 = *(const uint4*)&xp[(size_t)j0 * 128 + sub * 16];
        uint4 xb0 = *(const uint4*)&xp[(size_t)j0 * 128 + sub * 16 + 8];
        uint4 xa1 = *(const uint4*)&xp[(size_t)j1 * 128 + sub * 16];
        uint4 xb1 = *(const uint4*)&xp[(size_t)j1 * 128 + sub * 16 + 8];
        s0 = s0 > 0.f ? s0 : ALPHA_NEG * s0;
        s1 = s1 > 0.f ? s1 : ALPHA_NEG * s1;
        float w0 = __expf(-s0), w1 = __expf(-s1);
        rs += w0 + w1;
        unsigned ua0[4] = {xa0.x, xa0.y, xa0.z, xa0.w};
        unsigned ub0[4] = {xb0.x, xb0.y, xb0.z, xb0.w};
        unsigned ua1[4] = {xa1.x, xa1.y, xa1.z, xa1.w};
        unsigned ub1[4] = {xb1.x, xb1.y, xb1.z, xb1.w};
#pragma unroll
        for (int q = 0; q < 4; q++) {
            acc[2 * q]     += w0 * bflo(ua0[q]) + w1 * bflo(ua1[q]);
            acc[2 * q + 1] += w0 * bfhi(ua0[q]) + w1 * bfhi(ua1[q]);
            acc[8 + 2 * q]     += w0 * bflo(ub0[q]) + w1 * bflo(ub1[q]);
            acc[8 + 2 * q + 1] += w0 * bfhi(ub0[q]) + w1 * bfhi(ub1[q]);
        }
    }
    if (p < e1) {
        int j0 = dstp[p];
        float s0 = ssv + sdst[(size_t)j0 * 8 + h];
        uint4 xa0 = *(const uint4*)&xp[(size_t)j0 * 128 + sub * 16];
        uint4 xb0 = *(const uint4*)&xp[(size_t)j0 * 128 + sub * 16 + 8];
        s0 = s0 > 0.f ? s0 : ALPHA_NEG * s0;
        float w0 = __expf(-s0);
        rs += w0;
        unsigned ua0[4] = {xa0.x, xa0.y, xa0.z, xa0.w};
        unsigned ub0[4] = {xb0.x, xb0.y, xb0.z, xb0.w};
#pragma unroll
        for (int q = 0; q < 4; q++) {
            acc[2 * q]     += w0 * bflo(ua0[q]);
            acc[2 * q + 1] += w0 * bfhi(ua0[q]);
            acc[8 + 2 * q]     += w0 * bflo(ub0[q]);
            acc[8 + 2 * q + 1] += w0 * bfhi(ub0[q]);
        }
    }
    float inv = 1.0f / (rs + 1e-16f);
    // write z[i-n0, h*128 + sub*16 .. +15] as bf16 (two uint4 stores)
    uint4 o0, o1;
    unsigned* po0 = (unsigned*)&o0;
    unsigned* po1 = (unsigned*)&o1;
#pragma unroll
    for (int q = 0; q < 4; q++) {
        po0[q] = (unsigned)f2bf(acc[2 * q] * inv) | ((unsigned)f2bf(acc[2 * q + 1] * inv) << 16);
        po1[q] = (unsigned)f2bf(acc[8 + 2 * q] * inv) | ((unsigned)f2bf(acc[8 + 2 * q + 1] * inv) << 16);
    }
    size_t zb = (size_t)(i - n0) * 1024 + h * 128 + sub * 16;
    *(uint4*)&z[zb] = o0;
    *(uint4*)&z[zb + 8] = o1;
}

// ----------------------------- final-layer scores --------------------------
__global__ void scores2(const float* __restrict__ h2, const float* __restrict__ ae,
                        float* __restrict__ ss2, float* __restrict__ sd2, int n) {
    int t = threadIdx.x, wave = t >> 6, lane = t & 63;
    int i = blockIdx.x * 4 + wave;
    if (i >= n) return;
    float v = h2[(size_t)i * 64 + lane];
    float a = v * ae[lane];
    float b = v * ae[64 + lane];
    for (int d = 32; d > 0; d >>= 1) {
        a += __shfl_xor(a, d, 64);
        b += __shfl_xor(b, d, 64);
    }
    if (lane == 0) { ss2[i] = a; sd2[i] = b; }
}

// --------------------- final aggregation + row softmax ---------------------
__global__ void agg_final(const int* __restrict__ row_ptr, const int* __restrict__ dstp,
                          const float* __restrict__ ss2, const float* __restrict__ sd2,
                          const float* __restrict__ h2, float* __restrict__ out, int n) {
    int t = threadIdx.x, wave = t >> 6, lane = t & 63;
    int i = blockIdx.x * 4 + wave;
    if (i >= n) return;
    int e0 = row_ptr[i], e1 = row_ptr[i + 1];
    float ssrc = ss2[i];
    float acc = 0.f, rs = 0.f;
    int p = e0;
    for (; p + 4 <= e1; p += 4) {
        int j0 = dstp[p], j1 = dstp[p + 1], j2 = dstp[p + 2], j3 = dstp[p + 3];
        float s0 = ssrc + sd2[j0], s1 = ssrc + sd2[j1];
        float s2 = ssrc + sd2[j2], s3 = ssrc + sd2[j3];
        float v0 = h2[(size_t)j0 * 64 + lane], v1 = h2[(size_t)j1 * 64 + lane];
        float v2 = h2[(size_t)j2 * 64 + lane], v3 = h2[(size_t)j3 * 64 + lane];
        s0 = s0 > 0.f ? s0 : ALPHA_NEG * s0;
        s1 = s1 > 0.f ? s1 : ALPHA_NEG * s1;
        s2 = s2 > 0.f ? s2 : ALPHA_NEG * s2;
        s3 = s3 > 0.f ? s3 : ALPHA_NEG * s3;
        float w0 = __expf(-s0), w1 = __expf(-s1), w2 = __expf(-s2), w3 = __expf(-s3);
        rs += (w0 + w1) + (w2 + w3);
        acc += w0 * v0 + w1 * v1 + w2 * v2 + w3 * v3;
    }
    for (; p < e1; p++) {
        int j = dstp[p];
        float sc = ssrc + sd2[j];
        sc = sc > 0.f ? sc : ALPHA_NEG * sc;
        float w = __expf(-sc);
        acc += w * h2[(size_t)j * 64 + lane];
        rs += w;
    }
    float o = acc / (rs + 1e-16f);
    float m = o;
    for (int d = 32; d > 0; d >>= 1) m = fmaxf(m, __shfl_xor(m, d, 64));
    float e = __expf(o - m);
    float s = e;
    for (int d = 32; d > 0; d >>= 1) s += __shfl_xor(s, d, 64);
    out[(size_t)i * 64 + lane] = e / s;
}

// ------------------------------- launcher ----------------------------------
extern "C" void kernel_launch(void* const* d_in, const int* in_sizes, int n_in,
                              void* d_out, int out_size, void* d_ws, size_t ws_size,
                              hipStream_t stream) {
    const float* x  = (const float*)d_in[0];
    const int* edges = (const int*)d_in[1];
    const float* W0 = (const float*)d_in[2];
    const float* b0 = (const float*)d_in[3];
    const float* Wh = (const float*)d_in[4];
    const float* ah = (const float*)d_in[5];
    const float* We = (const float*)d_in[6];
    const float* ae = (const float*)d_in[7];
    float* dout = (float*)d_out;

    const int Nn = in_sizes[0] / 128;   // 100000
    const int E  = in_sizes[1] / 2;     // 1600000
    const int* src = edges;
    const int* dst = edges + E;

    char* p = (char*)d_ws;
    auto alloc = [&](size_t bytes) -> char* {
        char* r = p;
        p += (bytes + 255) & ~(size_t)255;
        return r;
    };
    unsigned short* W0t   = (unsigned short*)alloc(128 * 128 * 2);
    unsigned short* Ballt = (unsigned short*)alloc(512 * 128 * 2);
    unsigned short* Wendt = (unsigned short*)alloc((size_t)64 * 512 * 2);
    float* was   = (float*)alloc(1024 * 4);
    float* wad   = (float*)alloc(1024 * 4);
    int* deg     = (int*)alloc((size_t)Nn * 4);
    int* incl    = (int*)alloc((size_t)Nn * 4);
    int* part    = (int*)alloc(512 * 4);
    int* row_ptr = (int*)alloc((size_t)(Nn + 1) * 4);
    int* cursor  = (int*)alloc((size_t)Nn * 4);
    int* dstp    = (int*)alloc((size_t)E * 4);
    float* ssrc  = (float*)alloc((size_t)Nn * 8 * 4);
    float* sdst  = (float*)alloc((size_t)Nn * 8 * 4);
    float* ss2   = (float*)alloc((size_t)Nn * 4);
    float* sd2   = (float*)alloc((size_t)Nn * 4);
    unsigned short* xp = (unsigned short*)alloc((size_t)Nn * 128 * 2);
    unsigned short* z  = (unsigned short*)alloc((size_t)CHUNK * 1024 * 2); // h2 aliases
    unsigned short* hcat = (unsigned short*)alloc((size_t)Nn * 512 * 2);
    float* h2 = (float*)z;              // [N,64] fp32 = 25.6 MB <= z's 26.2 MB

    size_t needed = (size_t)(p - (char*)d_ws);
    if (needed > ws_size) return;       // diagnostic guard

    const int gm = (Nn + 127) / 128;
    const int nScanB = (Nn + SCAN_BS - 1) / SCAN_BS;

    hipMemsetAsync(deg, 0, (size_t)Nn * 4, stream);
    pack_w0<<<64, 256, 0, stream>>>(W0, W0t);
    pack_ball<<<256, 256, 0, stream>>>(Wh, Ballt);
    pack_wend<<<128, 256, 0, stream>>>(We, Wendt);
    pack_wa<<<4, 256, 0, stream>>>(Wh, ah, was, wad);

    edge_hist<<<(E + 255) / 256, 256, 0, stream>>>(src, deg, E);
    scan_blocks<<<nScanB, 256, 0, stream>>>(deg, incl, part, Nn);
    scan_partials<<<1, 512, 0, stream>>>(part, nScanB);
    finalize_rowptr<<<(Nn + 256) / 256, 256, 0, stream>>>(deg, incl, part, row_ptr, cursor, Nn, E);
    edge_scatter<<<(E + 255) / 256, 256, 0, stream>>>(src, dst, cursor, dstp, E);

    // xp = bf16(x @ W0 + b0)
    gemm_mfma<128, 128, 128, 2, 2, 4, 4, true, true, true, false, false>
        <<<dim3(gm, 1), 256, 0, stream>>>(x, W0t, b0, xp, Nn, 128, 128);

    // per-node per-head scores directly from xp
    scores_xp<<<(Nn + 3) / 4, 256, 0, stream>>>(xp, was, wad, ssrc, sdst, Nn);

    // chunked: z = normalized xp-aggregation; hcat = ELU(z_h @ W_h) per head
    for (int c0 = 0; c0 < Nn; c0 += CHUNK) {
        int c1 = min(c0 + CHUNK, Nn);
        int Mc = c1 - c0;
        agg_xp<<<(Mc + 3) / 4, 256, 0, stream>>>(row_ptr, dstp, ssrc, sdst, xp, z, c0, c1);
        gemm_mfma<128, 64, 128, 4, 1, 2, 4, false, false, true, true, true>
            <<<dim3((Mc + 127) / 128, 1, 8), 256, 0, stream>>>(
                z, Ballt, nullptr, hcat + (size_t)c0 * 512, Mc, 1024, 512);
    }

    // h2 = fp32(hcat @ W_end)  [N,64]   (h2 aliases z, now dead)
    gemm_mfma<128, 64, 512, 4, 1, 2, 4, false, false, false, false, false>
        <<<dim3(gm, 1), 256, 0, stream>>>(hcat, Wendt, nullptr, h2, Nn, 512, 64);

    scores2<<<(Nn + 3) / 4, 256, 0, stream>>>(h2, ae, ss2, sd2, Nn);
    agg_final<<<(Nn + 3) / 4, 256, 0, stream>>>(row_ptr, dstp, ss2, sd2, h2, dout, Nn);
}

// Round 5
// 821.043 us; speedup vs baseline: 1.1684x; 1.0547x over previous
//
#include <hip/hip_runtime.h>

// ---------------------------------------------------------------------------
// SpGAT: x@W0+b0 -> 8x GAT heads (concat 512) -> GAT(512->64) -> softmax.
// R4: aggregate xp (256 B/edge, all 8 heads at once) then per-head GEMM.
// R5: owner-computes CSR build — block b filters src into XCD-owned node
//     range (b&7); kills 16x dstp line ping-pong (WRITE_SIZE 105->~8 MB)
//     and makes cursor atomics L2-local.
// ---------------------------------------------------------------------------

using bf16x8 = __bf16 __attribute__((ext_vector_type(8)));
using f32x4  = float  __attribute__((ext_vector_type(4)));

__device__ __forceinline__ unsigned short f2bf(float f) {
    __bf16 h = (__bf16)f;                       // fptrunc, RNE
    return __builtin_bit_cast(unsigned short, h);
}
__device__ __forceinline__ float bflo(unsigned int u) {
    return __builtin_bit_cast(float, u << 16);
}
__device__ __forceinline__ float bfhi(unsigned int u) {
    return __builtin_bit_cast(float, u & 0xffff0000u);
}

#define ALPHA_NEG 0.2f
#define CHUNK 12800

// ------------------------------ pack kernels -------------------------------
__global__ void pack_w0(const float* __restrict__ W0, unsigned short* __restrict__ W0t) {
    int idx = blockIdx.x * 256 + threadIdx.x;      // 16384
    int n = idx >> 7, k = idx & 127;
    W0t[n * 128 + k] = f2bf(W0[k * 128 + n]);
}
// W_heads [8][128k][64f] fp32 -> Ballt [h][f][k] bf16  (= per-head B^T)
__global__ void pack_ball(const float* __restrict__ Wh, unsigned short* __restrict__ Bt) {
    int idx = blockIdx.x * 256 + threadIdx.x;      // 65536
    int c = idx >> 7, k = idx & 127;
    int h = c >> 6, f = c & 63;
    Bt[idx] = f2bf(Wh[(h * 128 + k) * 64 + f]);
}
__global__ void pack_wend(const float* __restrict__ We, unsigned short* __restrict__ Bt) {
    int idx = blockIdx.x * 256 + threadIdx.x;      // 32768
    int n = idx >> 9, k = idx & 511;
    Bt[idx] = f2bf(We[k * 64 + n]);
}
// w~_src[h][k] = sum_f W_h[k][f]*a_h[f];  w~_dst with a_h[64+f]
__global__ void pack_wa(const float* __restrict__ Wh, const float* __restrict__ ah,
                        float* __restrict__ was, float* __restrict__ wad) {
    int idx = blockIdx.x * 256 + threadIdx.x;      // 1024
    if (idx >= 1024) return;
    int h = idx >> 7, k = idx & 127;
    float s = 0.f, d = 0.f;
    for (int f = 0; f < 64; f++) {
        float wv = Wh[(h * 128 + k) * 64 + f];
        s += wv * ah[h * 128 + f];
        d += wv * ah[h * 128 + 64 + f];
    }
    was[idx] = s;
    wad[idx] = d;
}

// ---------------------- CSR build (owner-computes per XCD) -----------------
// Block b: edge chunk b>>3, node-range owner b&7. With round-robin block->XCD
// dispatch, all atomics/writes for a node range issue from one XCD (locality
// heuristic only — correctness is mapping-independent).
__global__ void edge_hist_own(const int* __restrict__ src, int* __restrict__ deg,
                              int E, int npo) {
    int owner = blockIdx.x & 7;
    int i = (blockIdx.x >> 3) * 256 + threadIdx.x;
    if (i >= E) return;
    int s = src[i];
    int lo = owner * npo;
    if (s >= lo && s < lo + npo) atomicAdd(&deg[s], 1);
}
__global__ void edge_scatter_own(const int* __restrict__ src, const int* __restrict__ dst,
                                 int* __restrict__ cursor, int* __restrict__ dstp,
                                 int E, int npo) {
    int owner = blockIdx.x & 7;
    int i = (blockIdx.x >> 3) * 256 + threadIdx.x;
    if (i >= E) return;
    int s = src[i];
    int lo = owner * npo;
    if (s >= lo && s < lo + npo) {
        int p = atomicAdd(&cursor[s], 1);
        dstp[p] = dst[i];
    }
}

#define SCAN_BS 256
__global__ void scan_blocks(const int* __restrict__ deg, int* __restrict__ incl,
                            int* __restrict__ partials, int n) {
    __shared__ int s[SCAN_BS];
    int t = threadIdx.x, i = blockIdx.x * SCAN_BS + t;
    int v = (i < n) ? deg[i] : 0;
    s[t] = v; __syncthreads();
    for (int off = 1; off < SCAN_BS; off <<= 1) {
        int add = (t >= off) ? s[t - off] : 0;
        __syncthreads();
        s[t] += add;
        __syncthreads();
    }
    if (i < n) incl[i] = s[t];
    if (t == SCAN_BS - 1) partials[blockIdx.x] = s[t];
}
__global__ void scan_partials(int* __restrict__ partials, int nb) {  // 1 block, 512 thr
    __shared__ int s[512];
    int t = threadIdx.x;
    int v = (t < nb) ? partials[t] : 0;
    s[t] = v; __syncthreads();
    for (int off = 1; off < 512; off <<= 1) {
        int add = (t >= off) ? s[t - off] : 0;
        __syncthreads();
        s[t] += add;
        __syncthreads();
    }
    if (t < nb) partials[t] = s[t] - v;   // exclusive block offset
}
__global__ void finalize_rowptr(const int* __restrict__ deg, const int* __restrict__ incl,
                                const int* __restrict__ partials, int* __restrict__ row_ptr,
                                int* __restrict__ cursor, int n, int E) {
    int i = blockIdx.x * 256 + threadIdx.x;
    if (i < n) {
        int v = incl[i] - deg[i] + partials[i / SCAN_BS];
        row_ptr[i] = v;
        cursor[i] = v;
    } else if (i == n) {
        row_ptr[n] = E;
    }
}

// ------------------------------- MFMA GEMM ---------------------------------
// C tile (BM x BN) = A[M,(lda)] * Bt[.,K]^T (+bias, opt ELU). bf16 in, fp32 acc.
// BATCHZ: blockIdx.z = head; A col offset z*K, B ptr offset z*BN*K, C col offset z*BN.
// A/B frag [idx=lane&15][k=(lane>>4)*8+j]; C/D col=lane&15, row=(lane>>4)*4+reg.
template <int BM, int BN, int K, int WM, int WN, int MT, int NT,
          bool AF32, bool BIAS, bool OBF16, bool ELU, bool BATCHZ>
__launch_bounds__(256)
__global__ void gemm_mfma(const void* __restrict__ Ap, const unsigned short* __restrict__ Bt,
                          const float* __restrict__ bias, void* __restrict__ Cp, int M,
                          int lda, int ldc) {
    constexpr int LDK = 40;                    // pad 32 -> 40 shorts (80B rows, 16B-aligned)
    __shared__ unsigned short As[BM * LDK];
    __shared__ unsigned short Bs[BN * LDK];
    const int t = threadIdx.x;
    const long m0 = (long)blockIdx.x * BM;
    const long n0 = (long)blockIdx.y * BN;
    const int abase = BATCHZ ? blockIdx.z * K : 0;
    const unsigned short* Btz = BATCHZ ? Bt + (size_t)blockIdx.z * BN * K : Bt;
    const long cbase = BATCHZ ? (long)blockIdx.z * BN : 0;
    const int wave = t >> 6, lane = t & 63;
    const int wm = wave / WN, wn = wave % WN;
    const int lrow = lane & 15, lq = lane >> 4;

    f32x4 acc[MT][NT];
#pragma unroll
    for (int a = 0; a < MT; a++)
#pragma unroll
        for (int b = 0; b < NT; b++) acc[a][b] = (f32x4)0.0f;

    for (int kt = 0; kt < K / 32; kt++) {
        const int k0 = kt * 32;
        if constexpr (AF32) {
            const float* A = (const float*)Ap;
#pragma unroll
            for (int it = 0; it < BM * 8 / 256; it++) {
                int L = t + 256 * it;
                int row = L >> 3, kc = (L & 7) * 4;
                long gr = m0 + row;
                float4 v = make_float4(0.f, 0.f, 0.f, 0.f);
                if (gr < M) v = *(const float4*)&A[gr * lda + abase + k0 + kc];
                unsigned int lo = (unsigned)f2bf(v.x) | ((unsigned)f2bf(v.y) << 16);
                unsigned int hi = (unsigned)f2bf(v.z) | ((unsigned)f2bf(v.w) << 16);
                *(uint2*)&As[row * LDK + kc] = make_uint2(lo, hi);
            }
        } else {
            const unsigned short* A = (const unsigned short*)Ap;
#pragma unroll
            for (int it = 0; it < BM * 4 / 256; it++) {
                int L = t + 256 * it;
                int row = L >> 2, kc = (L & 3) * 8;
                long gr = m0 + row;
                uint4 v = make_uint4(0u, 0u, 0u, 0u);
                if (gr < M) v = *(const uint4*)&A[gr * lda + abase + k0 + kc];
                *(uint4*)&As[row * LDK + kc] = v;
            }
        }
#pragma unroll
        for (int it = 0; it < BN * 4 / 256; it++) {
            int L = t + 256 * it;
            int row = L >> 2, kc = (L & 3) * 8;
            *(uint4*)&Bs[row * LDK + kc] = *(const uint4*)&Btz[(n0 + row) * K + k0 + kc];
        }
        __syncthreads();

        bf16x8 af[MT], bfr[NT];
#pragma unroll
        for (int mt = 0; mt < MT; mt++)
            af[mt] = *(const bf16x8*)&As[((wm * MT + mt) * 16 + lrow) * LDK + lq * 8];
#pragma unroll
        for (int nt = 0; nt < NT; nt++)
            bfr[nt] = *(const bf16x8*)&Bs[((wn * NT + nt) * 16 + lrow) * LDK + lq * 8];
#pragma unroll
        for (int mt = 0; mt < MT; mt++)
#pragma unroll
            for (int nt = 0; nt < NT; nt++)
                acc[mt][nt] = __builtin_amdgcn_mfma_f32_16x16x32_bf16(af[mt], bfr[nt],
                                                                     acc[mt][nt], 0, 0, 0);
        __syncthreads();
    }

#pragma unroll
    for (int mt = 0; mt < MT; mt++) {
        long rbase = m0 + (wm * MT + mt) * 16 + lq * 4;
#pragma unroll
        for (int nt = 0; nt < NT; nt++) {
            long col = cbase + n0 + (wn * NT + nt) * 16 + lrow;
            float bv = 0.f;
            if constexpr (BIAS) bv = bias[col];
#pragma unroll
            for (int r = 0; r < 4; r++) {
                long row = rbase + r;
                if (row < M) {
                    float v = acc[mt][nt][r] + bv;
                    if constexpr (ELU) v = v > 0.f ? v : __expf(v) - 1.0f;
                    if constexpr (OBF16)
                        ((unsigned short*)Cp)[row * ldc + col] = f2bf(v);
                    else
                        ((float*)Cp)[row * ldc + col] = v;
                }
            }
        }
    }
}

// ---------------- per-node per-head scores from xp and w~ ------------------
__global__ void scores_xp(const unsigned short* __restrict__ xp,
                          const float* __restrict__ was, const float* __restrict__ wad,
                          float* __restrict__ ssrc, float* __restrict__ sdst, int n) {
    int t = threadIdx.x, wave = t >> 6, lane = t & 63;
    int i = blockIdx.x * 4 + wave;
    if (i >= n) return;
    unsigned xv = *(const unsigned*)&xp[(size_t)i * 128 + 2 * lane];
    float x0 = bflo(xv), x1 = bfhi(xv);
    float sa[8], sb[8];
#pragma unroll
    for (int h = 0; h < 8; h++) {
        sa[h] = x0 * was[h * 128 + 2 * lane] + x1 * was[h * 128 + 2 * lane + 1];
        sb[h] = x0 * wad[h * 128 + 2 * lane] + x1 * wad[h * 128 + 2 * lane + 1];
    }
#pragma unroll
    for (int h = 0; h < 8; h++) {
        float a = sa[h], b = sb[h];
        for (int d = 32; d > 0; d >>= 1) {
            a += __shfl_xor(a, d, 64);
            b += __shfl_xor(b, d, 64);
        }
        sa[h] = a; sb[h] = b;
    }
    if (lane < 8) {
        float v = sa[0], w = sb[0];
#pragma unroll
        for (int h = 1; h < 8; h++)
            if (lane == h) { v = sa[h]; w = sb[h]; }
        ssrc[i * 8 + lane] = v;
        sdst[i * 8 + lane] = w;
    }
}

// ---------------- 8-head xp aggregation (chunked), zero shuffles -----------
// Wave per node. lane: head h=lane>>3, sub=lane&7 -> owns xp cols sub*16..+15.
__global__ void agg_xp(const int* __restrict__ row_ptr, const int* __restrict__ dstp,
                       const float* __restrict__ ssrc, const float* __restrict__ sdst,
                       const unsigned short* __restrict__ xp, unsigned short* __restrict__ z,
                       int n0, int n1) {
    int t = threadIdx.x, wave = t >> 6, lane = t & 63;
    int i = n0 + blockIdx.x * 4 + wave;
    if (i >= n1) return;
    int e0 = row_ptr[i], e1 = row_ptr[i + 1];
    int h = lane >> 3, sub = lane & 7;
    float ssv = ssrc[i * 8 + h];
    float acc[16];
#pragma unroll
    for (int c = 0; c < 16; c++) acc[c] = 0.f;
    float rs = 0.f;
    int p = e0;
    for (; p + 2 <= e1; p += 2) {
        int j0 = dstp[p], j1 = dstp[p + 1];
        float s0 = ssv + sdst[(size_t)j0 * 8 + h];
        float s1 = ssv + sdst[(size_t)j1 * 8 + h];
        uint4 xa0 = *(const uint4*)&xp[(size_t)j0 * 128 + sub * 16];
        uint4 xb0 = *(const uint4*)&xp[(size_t)j0 * 128 + sub * 16 + 8];
        uint4 xa1 = *(const uint4*)&xp[(size_t)j1 * 128 + sub * 16];
        uint4 xb1 = *(const uint4*)&xp[(size_t)j1 * 128 + sub * 16 + 8];
        s0 = s0 > 0.f ? s0 : ALPHA_NEG * s0;
        s1 = s1 > 0.f ? s1 : ALPHA_NEG * s1;
        float w0 = __expf(-s0), w1 = __expf(-s1);
        rs += w0 + w1;
        unsigned ua0[4] = {xa0.x, xa0.y, xa0.z, xa0.w};
        unsigned ub0[4] = {xb0.x, xb0.y, xb0.z, xb0.w};
        unsigned ua1[4] = {xa1.x, xa1.y, xa1.z, xa1.w};
        unsigned ub1[4] = {xb1.x, xb1.y, xb1.z, xb1.w};
#pragma unroll
        for (int q = 0; q < 4; q++) {
            acc[2 * q]     += w0 * bflo(ua0[q]) + w1 * bflo(ua1[q]);
            acc[2 * q + 1] += w0 * bfhi(ua0[q]) + w1 * bfhi(ua1[q]);
            acc[8 + 2 * q]     += w0 * bflo(ub0[q]) + w1 * bflo(ub1[q]);
            acc[8 + 2 * q + 1] += w0 * bfhi(ub0[q]) + w1 * bfhi(ub1[q]);
        }
    }
    if (p < e1) {
        int j0 = dstp[p];
        float s0 = ssv + sdst[(size_t)j0 * 8 + h];
        uint4 xa0 = *(const uint4*)&xp[(size_t)j0 * 128 + sub * 16];
        uint4 xb0 = *(const uint4*)&xp[(size_t)j0 * 128 + sub * 16 + 8];
        s0 = s0 > 0.f ? s0 : ALPHA_NEG * s0;
        float w0 = __expf(-s0);
        rs += w0;
        unsigned ua0[4] = {xa0.x, xa0.y, xa0.z, xa0.w};
        unsigned ub0[4] = {xb0.x, xb0.y, xb0.z, xb0.w};
#pragma unroll
        for (int q = 0; q < 4; q++) {
            acc[2 * q]     += w0 * bflo(ua0[q]);
            acc[2 * q + 1] += w0 * bfhi(ua0[q]);
            acc[8 + 2 * q]     += w0 * bflo(ub0[q]);
            acc[8 + 2 * q + 1] += w0 * bfhi(ub0[q]);
        }
    }
    float inv = 1.0f / (rs + 1e-16f);
    uint4 o0, o1;
    unsigned* po0 = (unsigned*)&o0;
    unsigned* po1 = (unsigned*)&o1;
#pragma unroll
    for (int q = 0; q < 4; q++) {
        po0[q] = (unsigned)f2bf(acc[2 * q] * inv) | ((unsigned)f2bf(acc[2 * q + 1] * inv) << 16);
        po1[q] = (unsigned)f2bf(acc[8 + 2 * q] * inv) | ((unsigned)f2bf(acc[8 + 2 * q + 1] * inv) << 16);
    }
    size_t zb = (size_t)(i - n0) * 1024 + h * 128 + sub * 16;
    *(uint4*)&z[zb] = o0;
    *(uint4*)&z[zb + 8] = o1;
}

// ----------------------------- final-layer scores --------------------------
__global__ void scores2(const float* __restrict__ h2, const float* __restrict__ ae,
                        float* __restrict__ ss2, float* __restrict__ sd2, int n) {
    int t = threadIdx.x, wave = t >> 6, lane = t & 63;
    int i = blockIdx.x * 4 + wave;
    if (i >= n) return;
    float v = h2[(size_t)i * 64 + lane];
    float a = v * ae[lane];
    float b = v * ae[64 + lane];
    for (int d = 32; d > 0; d >>= 1) {
        a += __shfl_xor(a, d, 64);
        b += __shfl_xor(b, d, 64);
    }
    if (lane == 0) { ss2[i] = a; sd2[i] = b; }
}

// --------------------- final aggregation + row softmax ---------------------
__global__ void agg_final(const int* __restrict__ row_ptr, const int* __restrict__ dstp,
                          const float* __restrict__ ss2, const float* __restrict__ sd2,
                          const float* __restrict__ h2, float* __restrict__ out, int n) {
    int t = threadIdx.x, wave = t >> 6, lane = t & 63;
    int i = blockIdx.x * 4 + wave;
    if (i >= n) return;
    int e0 = row_ptr[i], e1 = row_ptr[i + 1];
    float ssrc = ss2[i];
    float acc = 0.f, rs = 0.f;
    int p = e0;
    for (; p + 4 <= e1; p += 4) {
        int j0 = dstp[p], j1 = dstp[p + 1], j2 = dstp[p + 2], j3 = dstp[p + 3];
        float s0 = ssrc + sd2[j0], s1 = ssrc + sd2[j1];
        float s2 = ssrc + sd2[j2], s3 = ssrc + sd2[j3];
        float v0 = h2[(size_t)j0 * 64 + lane], v1 = h2[(size_t)j1 * 64 + lane];
        float v2 = h2[(size_t)j2 * 64 + lane], v3 = h2[(size_t)j3 * 64 + lane];
        s0 = s0 > 0.f ? s0 : ALPHA_NEG * s0;
        s1 = s1 > 0.f ? s1 : ALPHA_NEG * s1;
        s2 = s2 > 0.f ? s2 : ALPHA_NEG * s2;
        s3 = s3 > 0.f ? s3 : ALPHA_NEG * s3;
        float w0 = __expf(-s0), w1 = __expf(-s1), w2 = __expf(-s2), w3 = __expf(-s3);
        rs += (w0 + w1) + (w2 + w3);
        acc += w0 * v0 + w1 * v1 + w2 * v2 + w3 * v3;
    }
    for (; p < e1; p++) {
        int j = dstp[p];
        float sc = ssrc + sd2[j];
        sc = sc > 0.f ? sc : ALPHA_NEG * sc;
        float w = __expf(-sc);
        acc += w * h2[(size_t)j * 64 + lane];
        rs += w;
    }
    float o = acc / (rs + 1e-16f);
    float m = o;
    for (int d = 32; d > 0; d >>= 1) m = fmaxf(m, __shfl_xor(m, d, 64));
    float e = __expf(o - m);
    float s = e;
    for (int d = 32; d > 0; d >>= 1) s += __shfl_xor(s, d, 64);
    out[(size_t)i * 64 + lane] = e / s;
}

// ------------------------------- launcher ----------------------------------
extern "C" void kernel_launch(void* const* d_in, const int* in_sizes, int n_in,
                              void* d_out, int out_size, void* d_ws, size_t ws_size,
                              hipStream_t stream) {
    const float* x  = (const float*)d_in[0];
    const int* edges = (const int*)d_in[1];
    const float* W0 = (const float*)d_in[2];
    const float* b0 = (const float*)d_in[3];
    const float* Wh = (const float*)d_in[4];
    const float* ah = (const float*)d_in[5];
    const float* We = (const float*)d_in[6];
    const float* ae = (const float*)d_in[7];
    float* dout = (float*)d_out;

    const int Nn = in_sizes[0] / 128;   // 100000
    const int E  = in_sizes[1] / 2;     // 1600000
    const int* src = edges;
    const int* dst = edges + E;
    const int npo = (Nn + 7) / 8;       // nodes per XCD owner

    char* p = (char*)d_ws;
    auto alloc = [&](size_t bytes) -> char* {
        char* r = p;
        p += (bytes + 255) & ~(size_t)255;
        return r;
    };
    unsigned short* W0t   = (unsigned short*)alloc(128 * 128 * 2);
    unsigned short* Ballt = (unsigned short*)alloc(512 * 128 * 2);
    unsigned short* Wendt = (unsigned short*)alloc((size_t)64 * 512 * 2);
    float* was   = (float*)alloc(1024 * 4);
    float* wad   = (float*)alloc(1024 * 4);
    int* deg     = (int*)alloc((size_t)Nn * 4);
    int* incl    = (int*)alloc((size_t)Nn * 4);
    int* part    = (int*)alloc(512 * 4);
    int* row_ptr = (int*)alloc((size_t)(Nn + 1) * 4);
    int* cursor  = (int*)alloc((size_t)Nn * 4);
    int* dstp    = (int*)alloc((size_t)E * 4);
    float* ssrc  = (float*)alloc((size_t)Nn * 8 * 4);
    float* sdst  = (float*)alloc((size_t)Nn * 8 * 4);
    float* ss2   = (float*)alloc((size_t)Nn * 4);
    float* sd2   = (float*)alloc((size_t)Nn * 4);
    unsigned short* xp = (unsigned short*)alloc((size_t)Nn * 128 * 2);
    unsigned short* z  = (unsigned short*)alloc((size_t)CHUNK * 1024 * 2); // h2 aliases
    unsigned short* hcat = (unsigned short*)alloc((size_t)Nn * 512 * 2);
    float* h2 = (float*)z;              // [N,64] fp32 = 25.6 MB <= z's 26.2 MB

    size_t needed = (size_t)(p - (char*)d_ws);
    if (needed > ws_size) return;       // diagnostic guard

    const int gm = (Nn + 127) / 128;
    const int nScanB = (Nn + SCAN_BS - 1) / SCAN_BS;
    const int eb = (E + 255) / 256;     // edge chunks

    hipMemsetAsync(deg, 0, (size_t)Nn * 4, stream);
    pack_w0<<<64, 256, 0, stream>>>(W0, W0t);
    pack_ball<<<256, 256, 0, stream>>>(Wh, Ballt);
    pack_wend<<<128, 256, 0, stream>>>(We, Wendt);
    pack_wa<<<4, 256, 0, stream>>>(Wh, ah, was, wad);

    edge_hist_own<<<eb * 8, 256, 0, stream>>>(src, deg, E, npo);
    scan_blocks<<<nScanB, 256, 0, stream>>>(deg, incl, part, Nn);
    scan_partials<<<1, 512, 0, stream>>>(part, nScanB);
    finalize_rowptr<<<(Nn + 256) / 256, 256, 0, stream>>>(deg, incl, part, row_ptr, cursor, Nn, E);
    edge_scatter_own<<<eb * 8, 256, 0, stream>>>(src, dst, cursor, dstp, E, npo);

    // xp = bf16(x @ W0 + b0)
    gemm_mfma<128, 128, 128, 2, 2, 4, 4, true, true, true, false, false>
        <<<dim3(gm, 1), 256, 0, stream>>>(x, W0t, b0, xp, Nn, 128, 128);

    // per-node per-head scores directly from xp
    scores_xp<<<(Nn + 3) / 4, 256, 0, stream>>>(xp, was, wad, ssrc, sdst, Nn);

    // chunked: z = normalized xp-aggregation; hcat = ELU(z_h @ W_h) per head
    for (int c0 = 0; c0 < Nn; c0 += CHUNK) {
        int c1 = min(c0 + CHUNK, Nn);
        int Mc = c1 - c0;
        agg_xp<<<(Mc + 3) / 4, 256, 0, stream>>>(row_ptr, dstp, ssrc, sdst, xp, z, c0, c1);
        gemm_mfma<128, 64, 128, 4, 1, 2, 4, false, false, true, true, true>
            <<<dim3((Mc + 127) / 128, 1, 8), 256, 0, stream>>>(
                z, Ballt, nullptr, hcat + (size_t)c0 * 512, Mc, 1024, 512);
    }

    // h2 = fp32(hcat @ W_end)  [N,64]   (h2 aliases z, now dead)
    gemm_mfma<128, 64, 512, 4, 1, 2, 4, false, false, false, false, false>
        <<<dim3(gm, 1), 256, 0, stream>>>(hcat, Wendt, nullptr, h2, Nn, 512, 64);

    scores2<<<(Nn + 3) / 4, 256, 0, stream>>>(h2, ae, ss2, sd2, Nn);
    agg_final<<<(Nn + 3) / 4, 256, 0, stream>>>(row_ptr, dstp, ss2, sd2, h2, dout, Nn);
}

// Round 6
// 738.900 us; speedup vs baseline: 1.2983x; 1.1112x over previous
//
#include <hip/hip_runtime.h>

// ---------------------------------------------------------------------------
// SpGAT: x@W0+b0 -> 8x GAT heads (concat 512) -> GAT(512->64) -> softmax.
// R4: aggregate xp (256 B/edge, all 8 heads at once) then per-head GEMM.
// R5: owner-computes CSR build (per-XCD node ranges).
// R6: head scores via MFMA GEMM  s16[N,16] = xp @ [was||wad]^T  — replaces
//     the DS-pipe-bound 96-shuffle scores_xp kernel (108 us -> ~10 us).
// ---------------------------------------------------------------------------

using bf16x8 = __bf16 __attribute__((ext_vector_type(8)));
using f32x4  = float  __attribute__((ext_vector_type(4)));

__device__ __forceinline__ unsigned short f2bf(float f) {
    __bf16 h = (__bf16)f;                       // fptrunc, RNE
    return __builtin_bit_cast(unsigned short, h);
}
__device__ __forceinline__ float bflo(unsigned int u) {
    return __builtin_bit_cast(float, u << 16);
}
__device__ __forceinline__ float bfhi(unsigned int u) {
    return __builtin_bit_cast(float, u & 0xffff0000u);
}

#define ALPHA_NEG 0.2f
#define CHUNK 12800

// ------------------------------ pack kernels -------------------------------
__global__ void pack_w0(const float* __restrict__ W0, unsigned short* __restrict__ W0t) {
    int idx = blockIdx.x * 256 + threadIdx.x;      // 16384
    int n = idx >> 7, k = idx & 127;
    W0t[n * 128 + k] = f2bf(W0[k * 128 + n]);
}
// W_heads [8][128k][64f] fp32 -> Ballt [h][f][k] bf16  (= per-head B^T)
__global__ void pack_ball(const float* __restrict__ Wh, unsigned short* __restrict__ Bt) {
    int idx = blockIdx.x * 256 + threadIdx.x;      // 65536
    int c = idx >> 7, k = idx & 127;
    int h = c >> 6, f = c & 63;
    Bt[idx] = f2bf(Wh[(h * 128 + k) * 64 + f]);
}
__global__ void pack_wend(const float* __restrict__ We, unsigned short* __restrict__ Bt) {
    int idx = blockIdx.x * 256 + threadIdx.x;      // 32768
    int n = idx >> 9, k = idx & 511;
    Bt[idx] = f2bf(We[k * 64 + n]);
}
// Bscore[16][128] bf16: row h   = w~_src[h][k] = sum_f W_h[k][f]*a_h[f]
//                       row 8+h = w~_dst[h][k] (a_h[64+f])
__global__ void pack_wa(const float* __restrict__ Wh, const float* __restrict__ ah,
                        unsigned short* __restrict__ Bscore) {
    int idx = blockIdx.x * 256 + threadIdx.x;      // 1024
    if (idx >= 1024) return;
    int h = idx >> 7, k = idx & 127;
    float s = 0.f, d = 0.f;
    for (int f = 0; f < 64; f++) {
        float wv = Wh[(h * 128 + k) * 64 + f];
        s += wv * ah[h * 128 + f];
        d += wv * ah[h * 128 + 64 + f];
    }
    Bscore[h * 128 + k] = f2bf(s);
    Bscore[(8 + h) * 128 + k] = f2bf(d);
}

// ---------------------- CSR build (owner-computes per XCD) -----------------
__global__ void edge_hist_own(const int* __restrict__ src, int* __restrict__ deg,
                              int E, int npo) {
    int owner = blockIdx.x & 7;
    int i = (blockIdx.x >> 3) * 256 + threadIdx.x;
    if (i >= E) return;
    int s = src[i];
    int lo = owner * npo;
    if (s >= lo && s < lo + npo) atomicAdd(&deg[s], 1);
}
__global__ void edge_scatter_own(const int* __restrict__ src, const int* __restrict__ dst,
                                 int* __restrict__ cursor, int* __restrict__ dstp,
                                 int E, int npo) {
    int owner = blockIdx.x & 7;
    int i = (blockIdx.x >> 3) * 256 + threadIdx.x;
    if (i >= E) return;
    int s = src[i];
    int lo = owner * npo;
    if (s >= lo && s < lo + npo) {
        int p = atomicAdd(&cursor[s], 1);
        dstp[p] = dst[i];
    }
}

#define SCAN_BS 256
__global__ void scan_blocks(const int* __restrict__ deg, int* __restrict__ incl,
                            int* __restrict__ partials, int n) {
    __shared__ int s[SCAN_BS];
    int t = threadIdx.x, i = blockIdx.x * SCAN_BS + t;
    int v = (i < n) ? deg[i] : 0;
    s[t] = v; __syncthreads();
    for (int off = 1; off < SCAN_BS; off <<= 1) {
        int add = (t >= off) ? s[t - off] : 0;
        __syncthreads();
        s[t] += add;
        __syncthreads();
    }
    if (i < n) incl[i] = s[t];
    if (t == SCAN_BS - 1) partials[blockIdx.x] = s[t];
}
__global__ void scan_partials(int* __restrict__ partials, int nb) {  // 1 block, 512 thr
    __shared__ int s[512];
    int t = threadIdx.x;
    int v = (t < nb) ? partials[t] : 0;
    s[t] = v; __syncthreads();
    for (int off = 1; off < 512; off <<= 1) {
        int add = (t >= off) ? s[t - off] : 0;
        __syncthreads();
        s[t] += add;
        __syncthreads();
    }
    if (t < nb) partials[t] = s[t] - v;   // exclusive block offset
}
__global__ void finalize_rowptr(const int* __restrict__ deg, const int* __restrict__ incl,
                                const int* __restrict__ partials, int* __restrict__ row_ptr,
                                int* __restrict__ cursor, int n, int E) {
    int i = blockIdx.x * 256 + threadIdx.x;
    if (i < n) {
        int v = incl[i] - deg[i] + partials[i / SCAN_BS];
        row_ptr[i] = v;
        cursor[i] = v;
    } else if (i == n) {
        row_ptr[n] = E;
    }
}

// ------------------------------- MFMA GEMM ---------------------------------
// C tile (BM x BN) = A[M,(lda)] * Bt[.,K]^T (+bias, opt ELU). bf16 in, fp32 acc.
// BATCHZ: blockIdx.z = head; A col offset z*K, B ptr offset z*BN*K, C col offset z*BN.
// A/B frag [idx=lane&15][k=(lane>>4)*8+j]; C/D col=lane&15, row=(lane>>4)*4+reg.
template <int BM, int BN, int K, int WM, int WN, int MT, int NT,
          bool AF32, bool BIAS, bool OBF16, bool ELU, bool BATCHZ>
__launch_bounds__(256)
__global__ void gemm_mfma(const void* __restrict__ Ap, const unsigned short* __restrict__ Bt,
                          const float* __restrict__ bias, void* __restrict__ Cp, int M,
                          int lda, int ldc) {
    constexpr int LDK = 40;                    // pad 32 -> 40 shorts (80B rows, 16B-aligned)
    __shared__ unsigned short As[BM * LDK];
    __shared__ unsigned short Bs[BN * LDK];
    const int t = threadIdx.x;
    const long m0 = (long)blockIdx.x * BM;
    const long n0 = (long)blockIdx.y * BN;
    const int abase = BATCHZ ? blockIdx.z * K : 0;
    const unsigned short* Btz = BATCHZ ? Bt + (size_t)blockIdx.z * BN * K : Bt;
    const long cbase = BATCHZ ? (long)blockIdx.z * BN : 0;
    const int wave = t >> 6, lane = t & 63;
    const int wm = wave / WN, wn = wave % WN;
    const int lrow = lane & 15, lq = lane >> 4;

    f32x4 acc[MT][NT];
#pragma unroll
    for (int a = 0; a < MT; a++)
#pragma unroll
        for (int b = 0; b < NT; b++) acc[a][b] = (f32x4)0.0f;

    for (int kt = 0; kt < K / 32; kt++) {
        const int k0 = kt * 32;
        if constexpr (AF32) {
            const float* A = (const float*)Ap;
#pragma unroll
            for (int it = 0; it < BM * 8 / 256; it++) {
                int L = t + 256 * it;
                int row = L >> 3, kc = (L & 7) * 4;
                long gr = m0 + row;
                float4 v = make_float4(0.f, 0.f, 0.f, 0.f);
                if (gr < M) v = *(const float4*)&A[gr * lda + abase + k0 + kc];
                unsigned int lo = (unsigned)f2bf(v.x) | ((unsigned)f2bf(v.y) << 16);
                unsigned int hi = (unsigned)f2bf(v.z) | ((unsigned)f2bf(v.w) << 16);
                *(uint2*)&As[row * LDK + kc] = make_uint2(lo, hi);
            }
        } else {
            const unsigned short* A = (const unsigned short*)Ap;
#pragma unroll
            for (int it = 0; it < BM * 4 / 256; it++) {
                int L = t + 256 * it;
                int row = L >> 2, kc = (L & 3) * 8;
                long gr = m0 + row;
                uint4 v = make_uint4(0u, 0u, 0u, 0u);
                if (gr < M) v = *(const uint4*)&A[gr * lda + abase + k0 + kc];
                *(uint4*)&As[row * LDK + kc] = v;
            }
        }
#pragma unroll
        for (int it = 0; it < (BN * 4 + 255) / 256; it++) {
            int L = t + 256 * it;
            if (L < BN * 4) {
                int row = L >> 2, kc = (L & 3) * 8;
                *(uint4*)&Bs[row * LDK + kc] = *(const uint4*)&Btz[(n0 + row) * K + k0 + kc];
            }
        }
        __syncthreads();

        bf16x8 af[MT], bfr[NT];
#pragma unroll
        for (int mt = 0; mt < MT; mt++)
            af[mt] = *(const bf16x8*)&As[((wm * MT + mt) * 16 + lrow) * LDK + lq * 8];
#pragma unroll
        for (int nt = 0; nt < NT; nt++)
            bfr[nt] = *(const bf16x8*)&Bs[((wn * NT + nt) * 16 + lrow) * LDK + lq * 8];
#pragma unroll
        for (int mt = 0; mt < MT; mt++)
#pragma unroll
            for (int nt = 0; nt < NT; nt++)
                acc[mt][nt] = __builtin_amdgcn_mfma_f32_16x16x32_bf16(af[mt], bfr[nt],
                                                                     acc[mt][nt], 0, 0, 0);
        __syncthreads();
    }

#pragma unroll
    for (int mt = 0; mt < MT; mt++) {
        long rbase = m0 + (wm * MT + mt) * 16 + lq * 4;
#pragma unroll
        for (int nt = 0; nt < NT; nt++) {
            long col = cbase + n0 + (wn * NT + nt) * 16 + lrow;
            float bv = 0.f;
            if constexpr (BIAS) bv = bias[col];
#pragma unroll
            for (int r = 0; r < 4; r++) {
                long row = rbase + r;
                if (row < M) {
                    float v = acc[mt][nt][r] + bv;
                    if constexpr (ELU) v = v > 0.f ? v : __expf(v) - 1.0f;
                    if constexpr (OBF16)
                        ((unsigned short*)Cp)[row * ldc + col] = f2bf(v);
                    else
                        ((float*)Cp)[row * ldc + col] = v;
                }
            }
        }
    }
}

// ---------------- 8-head xp aggregation (chunked), zero shuffles -----------
// Wave per node. lane: head h=lane>>3, sub=lane&7 -> owns xp cols sub*16..+15.
// s16[i][0..7]=src scores, s16[i][8..15]=dst scores.
__global__ void agg_xp(const int* __restrict__ row_ptr, const int* __restrict__ dstp,
                       const float* __restrict__ s16,
                       const unsigned short* __restrict__ xp, unsigned short* __restrict__ z,
                       int n0, int n1) {
    int t = threadIdx.x, wave = t >> 6, lane = t & 63;
    int i = n0 + blockIdx.x * 4 + wave;
    if (i >= n1) return;
    int e0 = row_ptr[i], e1 = row_ptr[i + 1];
    int h = lane >> 3, sub = lane & 7;
    float ssv = s16[(size_t)i * 16 + h];
    float acc[16];
#pragma unroll
    for (int c = 0; c < 16; c++) acc[c] = 0.f;
    float rs = 0.f;
    int p = e0;
    for (; p + 2 <= e1; p += 2) {
        int j0 = dstp[p], j1 = dstp[p + 1];
        float s0 = ssv + s16[(size_t)j0 * 16 + 8 + h];
        float s1 = ssv + s16[(size_t)j1 * 16 + 8 + h];
        uint4 xa0 = *(const uint4*)&xp[(size_t)j0 * 128 + sub * 16];
        uint4 xb0 = *(const uint4*)&xp[(size_t)j0 * 128 + sub * 16 + 8];
        uint4 xa1 = *(const uint4*)&xp[(size_t)j1 * 128 + sub * 16];
        uint4 xb1 = *(const uint4*)&xp[(size_t)j1 * 128 + sub * 16 + 8];
        s0 = s0 > 0.f ? s0 : ALPHA_NEG * s0;
        s1 = s1 > 0.f ? s1 : ALPHA_NEG * s1;
        float w0 = __expf(-s0), w1 = __expf(-s1);
        rs += w0 + w1;
        unsigned ua0[4] = {xa0.x, xa0.y, xa0.z, xa0.w};
        unsigned ub0[4] = {xb0.x, xb0.y, xb0.z, xb0.w};
        unsigned ua1[4] = {xa1.x, xa1.y, xa1.z, xa1.w};
        unsigned ub1[4] = {xb1.x, xb1.y, xb1.z, xb1.w};
#pragma unroll
        for (int q = 0; q < 4; q++) {
            acc[2 * q]     += w0 * bflo(ua0[q]) + w1 * bflo(ua1[q]);
            acc[2 * q + 1] += w0 * bfhi(ua0[q]) + w1 * bfhi(ua1[q]);
            acc[8 + 2 * q]     += w0 * bflo(ub0[q]) + w1 * bflo(ub1[q]);
            acc[8 + 2 * q + 1] += w0 * bfhi(ub0[q]) + w1 * bfhi(ub1[q]);
        }
    }
    if (p < e1) {
        int j0 = dstp[p];
        float s0 = ssv + s16[(size_t)j0 * 16 + 8 + h];
        uint4 xa0 = *(const uint4*)&xp[(size_t)j0 * 128 + sub * 16];
        uint4 xb0 = *(const uint4*)&xp[(size_t)j0 * 128 + sub * 16 + 8];
        s0 = s0 > 0.f ? s0 : ALPHA_NEG * s0;
        float w0 = __expf(-s0);
        rs += w0;
        unsigned ua0[4] = {xa0.x, xa0.y, xa0.z, xa0.w};
        unsigned ub0[4] = {xb0.x, xb0.y, xb0.z, xb0.w};
#pragma unroll
        for (int q = 0; q < 4; q++) {
            acc[2 * q]     += w0 * bflo(ua0[q]);
            acc[2 * q + 1] += w0 * bfhi(ua0[q]);
            acc[8 + 2 * q]     += w0 * bflo(ub0[q]);
            acc[8 + 2 * q + 1] += w0 * bfhi(ub0[q]);
        }
    }
    float inv = 1.0f / (rs + 1e-16f);
    uint4 o0, o1;
    unsigned* po0 = (unsigned*)&o0;
    unsigned* po1 = (unsigned*)&o1;
#pragma unroll
    for (int q = 0; q < 4; q++) {
        po0[q] = (unsigned)f2bf(acc[2 * q] * inv) | ((unsigned)f2bf(acc[2 * q + 1] * inv) << 16);
        po1[q] = (unsigned)f2bf(acc[8 + 2 * q] * inv) | ((unsigned)f2bf(acc[8 + 2 * q + 1] * inv) << 16);
    }
    size_t zb = (size_t)(i - n0) * 1024 + h * 128 + sub * 16;
    *(uint4*)&z[zb] = o0;
    *(uint4*)&z[zb + 8] = o1;
}

// ----------------------------- final-layer scores --------------------------
__global__ void scores2(const float* __restrict__ h2, const float* __restrict__ ae,
                        float* __restrict__ ss2, float* __restrict__ sd2, int n) {
    int t = threadIdx.x, wave = t >> 6, lane = t & 63;
    int i = blockIdx.x * 4 + wave;
    if (i >= n) return;
    float v = h2[(size_t)i * 64 + lane];
    float a = v * ae[lane];
    float b = v * ae[64 + lane];
    for (int d = 32; d > 0; d >>= 1) {
        a += __shfl_xor(a, d, 64);
        b += __shfl_xor(b, d, 64);
    }
    if (lane == 0) { ss2[i] = a; sd2[i] = b; }
}

// --------------------- final aggregation + row softmax ---------------------
__global__ void agg_final(const int* __restrict__ row_ptr, const int* __restrict__ dstp,
                          const float* __restrict__ ss2, const float* __restrict__ sd2,
                          const float* __restrict__ h2, float* __restrict__ out, int n) {
    int t = threadIdx.x, wave = t >> 6, lane = t & 63;
    int i = blockIdx.x * 4 + wave;
    if (i >= n) return;
    int e0 = row_ptr[i], e1 = row_ptr[i + 1];
    float ssrc = ss2[i];
    float acc = 0.f, rs = 0.f;
    int p = e0;
    for (; p + 4 <= e1; p += 4) {
        int j0 = dstp[p], j1 = dstp[p + 1], j2 = dstp[p + 2], j3 = dstp[p + 3];
        float s0 = ssrc + sd2[j0], s1 = ssrc + sd2[j1];
        float s2 = ssrc + sd2[j2], s3 = ssrc + sd2[j3];
        float v0 = h2[(size_t)j0 * 64 + lane], v1 = h2[(size_t)j1 * 64 + lane];
        float v2 = h2[(size_t)j2 * 64 + lane], v3 = h2[(size_t)j3 * 64 + lane];
        s0 = s0 > 0.f ? s0 : ALPHA_NEG * s0;
        s1 = s1 > 0.f ? s1 : ALPHA_NEG * s1;
        s2 = s2 > 0.f ? s2 : ALPHA_NEG * s2;
        s3 = s3 > 0.f ? s3 : ALPHA_NEG * s3;
        float w0 = __expf(-s0), w1 = __expf(-s1), w2 = __expf(-s2), w3 = __expf(-s3);
        rs += (w0 + w1) + (w2 + w3);
        acc += w0 * v0 + w1 * v1 + w2 * v2 + w3 * v3;
    }
    for (; p < e1; p++) {
        int j = dstp[p];
        float sc = ssrc + sd2[j];
        sc = sc > 0.f ? sc : ALPHA_NEG * sc;
        float w = __expf(-sc);
        acc += w * h2[(size_t)j * 64 + lane];
        rs += w;
    }
    float o = acc / (rs + 1e-16f);
    float m = o;
    for (int d = 32; d > 0; d >>= 1) m = fmaxf(m, __shfl_xor(m, d, 64));
    float e = __expf(o - m);
    float s = e;
    for (int d = 32; d > 0; d >>= 1) s += __shfl_xor(s, d, 64);
    out[(size_t)i * 64 + lane] = e / s;
}

// ------------------------------- launcher ----------------------------------
extern "C" void kernel_launch(void* const* d_in, const int* in_sizes, int n_in,
                              void* d_out, int out_size, void* d_ws, size_t ws_size,
                              hipStream_t stream) {
    const float* x  = (const float*)d_in[0];
    const int* edges = (const int*)d_in[1];
    const float* W0 = (const float*)d_in[2];
    const float* b0 = (const float*)d_in[3];
    const float* Wh = (const float*)d_in[4];
    const float* ah = (const float*)d_in[5];
    const float* We = (const float*)d_in[6];
    const float* ae = (const float*)d_in[7];
    float* dout = (float*)d_out;

    const int Nn = in_sizes[0] / 128;   // 100000
    const int E  = in_sizes[1] / 2;     // 1600000
    const int* src = edges;
    const int* dst = edges + E;
    const int npo = (Nn + 7) / 8;       // nodes per XCD owner

    char* p = (char*)d_ws;
    auto alloc = [&](size_t bytes) -> char* {
        char* r = p;
        p += (bytes + 255) & ~(size_t)255;
        return r;
    };
    unsigned short* W0t   = (unsigned short*)alloc(128 * 128 * 2);
    unsigned short* Ballt = (unsigned short*)alloc(512 * 128 * 2);
    unsigned short* Wendt = (unsigned short*)alloc((size_t)64 * 512 * 2);
    unsigned short* Bscore = (unsigned short*)alloc(16 * 128 * 2);
    int* deg     = (int*)alloc((size_t)Nn * 4);
    int* incl    = (int*)alloc((size_t)Nn * 4);
    int* part    = (int*)alloc(512 * 4);
    int* row_ptr = (int*)alloc((size_t)(Nn + 1) * 4);
    int* cursor  = (int*)alloc((size_t)Nn * 4);
    int* dstp    = (int*)alloc((size_t)E * 4);
    float* s16   = (float*)alloc((size_t)Nn * 16 * 4);
    float* ss2   = (float*)alloc((size_t)Nn * 4);
    float* sd2   = (float*)alloc((size_t)Nn * 4);
    unsigned short* xp = (unsigned short*)alloc((size_t)Nn * 128 * 2);
    unsigned short* z  = (unsigned short*)alloc((size_t)CHUNK * 1024 * 2); // h2 aliases
    unsigned short* hcat = (unsigned short*)alloc((size_t)Nn * 512 * 2);
    float* h2 = (float*)z;              // [N,64] fp32 = 25.6 MB <= z's 26.2 MB

    size_t needed = (size_t)(p - (char*)d_ws);
    if (needed > ws_size) return;       // diagnostic guard

    const int gm = (Nn + 127) / 128;
    const int nScanB = (Nn + SCAN_BS - 1) / SCAN_BS;
    const int eb = (E + 255) / 256;     // edge chunks

    hipMemsetAsync(deg, 0, (size_t)Nn * 4, stream);
    pack_w0<<<64, 256, 0, stream>>>(W0, W0t);
    pack_ball<<<256, 256, 0, stream>>>(Wh, Ballt);
    pack_wend<<<128, 256, 0, stream>>>(We, Wendt);
    pack_wa<<<4, 256, 0, stream>>>(Wh, ah, Bscore);

    edge_hist_own<<<eb * 8, 256, 0, stream>>>(src, deg, E, npo);
    scan_blocks<<<nScanB, 256, 0, stream>>>(deg, incl, part, Nn);
    scan_partials<<<1, 512, 0, stream>>>(part, nScanB);
    finalize_rowptr<<<(Nn + 256) / 256, 256, 0, stream>>>(deg, incl, part, row_ptr, cursor, Nn, E);
    edge_scatter_own<<<eb * 8, 256, 0, stream>>>(src, dst, cursor, dstp, E, npo);

    // xp = bf16(x @ W0 + b0)
    gemm_mfma<128, 128, 128, 2, 2, 4, 4, true, true, true, false, false>
        <<<dim3(gm, 1), 256, 0, stream>>>(x, W0t, b0, xp, Nn, 128, 128);

    // s16[N,16] = xp @ Bscore^T  (cols 0..7 = src scores, 8..15 = dst scores)
    gemm_mfma<128, 16, 128, 4, 1, 2, 1, false, false, false, false, false>
        <<<dim3(gm, 1), 256, 0, stream>>>(xp, Bscore, nullptr, s16, Nn, 128, 16);

    // chunked: z = normalized xp-aggregation; hcat = ELU(z_h @ W_h) per head
    for (int c0 = 0; c0 < Nn; c0 += CHUNK) {
        int c1 = min(c0 + CHUNK, Nn);
        int Mc = c1 - c0;
        agg_xp<<<(Mc + 3) / 4, 256, 0, stream>>>(row_ptr, dstp, s16, xp, z, c0, c1);
        gemm_mfma<128, 64, 128, 4, 1, 2, 4, false, false, true, true, true>
            <<<dim3((Mc + 127) / 128, 1, 8), 256, 0, stream>>>(
                z, Ballt, nullptr, hcat + (size_t)c0 * 512, Mc, 1024, 512);
    }

    // h2 = fp32(hcat @ W_end)  [N,64]   (h2 aliases z, now dead)
    gemm_mfma<128, 64, 512, 4, 1, 2, 4, false, false, false, false, false>
        <<<dim3(gm, 1), 256, 0, stream>>>(hcat, Wendt, nullptr, h2, Nn, 512, 64);

    scores2<<<(Nn + 3) / 4, 256, 0, stream>>>(h2, ae, ss2, sd2, Nn);
    agg_final<<<(Nn + 3) / 4, 256, 0, stream>>>(row_ptr, dstp, ss2, sd2, h2, dout, Nn);
}

// Round 7
// 715.272 us; speedup vs baseline: 1.3412x; 1.0330x over previous
//
#include <hip/hip_runtime.h>

// ---------------------------------------------------------------------------
// SpGAT: x@W0+b0 -> 8x GAT heads (concat 512) -> GAT(512->64) -> softmax.
// R4: aggregate xp (256 B/edge, all 8 heads at once) then per-head GEMM.
// R5: owner-computes CSR build (per-XCD node ranges).
// R6: head scores via MFMA GEMM s16 = xp @ [was||wad]^T.
// R7: h2 stored bf16 (halves agg_final gather), CHUNK 20000 (5 chunks),
//     agg_xp 4-edge unroll for deeper MLP.
// ---------------------------------------------------------------------------

using bf16x8 = __bf16 __attribute__((ext_vector_type(8)));
using f32x4  = float  __attribute__((ext_vector_type(4)));

__device__ __forceinline__ unsigned short f2bf(float f) {
    __bf16 h = (__bf16)f;                       // fptrunc, RNE
    return __builtin_bit_cast(unsigned short, h);
}
__device__ __forceinline__ float bflo(unsigned int u) {
    return __builtin_bit_cast(float, u << 16);
}
__device__ __forceinline__ float bfhi(unsigned int u) {
    return __builtin_bit_cast(float, u & 0xffff0000u);
}
__device__ __forceinline__ float bfs(unsigned short u) {
    return __builtin_bit_cast(float, (unsigned)u << 16);
}

#define ALPHA_NEG 0.2f
#define CHUNK 20000

// ------------------------------ pack kernels -------------------------------
__global__ void pack_w0(const float* __restrict__ W0, unsigned short* __restrict__ W0t) {
    int idx = blockIdx.x * 256 + threadIdx.x;      // 16384
    int n = idx >> 7, k = idx & 127;
    W0t[n * 128 + k] = f2bf(W0[k * 128 + n]);
}
// W_heads [8][128k][64f] fp32 -> Ballt [h][f][k] bf16  (= per-head B^T)
__global__ void pack_ball(const float* __restrict__ Wh, unsigned short* __restrict__ Bt) {
    int idx = blockIdx.x * 256 + threadIdx.x;      // 65536
    int c = idx >> 7, k = idx & 127;
    int h = c >> 6, f = c & 63;
    Bt[idx] = f2bf(Wh[(h * 128 + k) * 64 + f]);
}
__global__ void pack_wend(const float* __restrict__ We, unsigned short* __restrict__ Bt) {
    int idx = blockIdx.x * 256 + threadIdx.x;      // 32768
    int n = idx >> 9, k = idx & 511;
    Bt[idx] = f2bf(We[k * 64 + n]);
}
// Bscore[16][128] bf16: row h = w~_src[h][k]; row 8+h = w~_dst[h][k]
__global__ void pack_wa(const float* __restrict__ Wh, const float* __restrict__ ah,
                        unsigned short* __restrict__ Bscore) {
    int idx = blockIdx.x * 256 + threadIdx.x;      // 1024
    if (idx >= 1024) return;
    int h = idx >> 7, k = idx & 127;
    float s = 0.f, d = 0.f;
    for (int f = 0; f < 64; f++) {
        float wv = Wh[(h * 128 + k) * 64 + f];
        s += wv * ah[h * 128 + f];
        d += wv * ah[h * 128 + 64 + f];
    }
    Bscore[h * 128 + k] = f2bf(s);
    Bscore[(8 + h) * 128 + k] = f2bf(d);
}

// ---------------------- CSR build (owner-computes per XCD) -----------------
__global__ void edge_hist_own(const int* __restrict__ src, int* __restrict__ deg,
                              int E, int npo) {
    int owner = blockIdx.x & 7;
    int i = (blockIdx.x >> 3) * 256 + threadIdx.x;
    if (i >= E) return;
    int s = src[i];
    int lo = owner * npo;
    if (s >= lo && s < lo + npo) atomicAdd(&deg[s], 1);
}
__global__ void edge_scatter_own(const int* __restrict__ src, const int* __restrict__ dst,
                                 int* __restrict__ cursor, int* __restrict__ dstp,
                                 int E, int npo) {
    int owner = blockIdx.x & 7;
    int i = (blockIdx.x >> 3) * 256 + threadIdx.x;
    if (i >= E) return;
    int s = src[i];
    int lo = owner * npo;
    if (s >= lo && s < lo + npo) {
        int p = atomicAdd(&cursor[s], 1);
        dstp[p] = dst[i];
    }
}

#define SCAN_BS 256
__global__ void scan_blocks(const int* __restrict__ deg, int* __restrict__ incl,
                            int* __restrict__ partials, int n) {
    __shared__ int s[SCAN_BS];
    int t = threadIdx.x, i = blockIdx.x * SCAN_BS + t;
    int v = (i < n) ? deg[i] : 0;
    s[t] = v; __syncthreads();
    for (int off = 1; off < SCAN_BS; off <<= 1) {
        int add = (t >= off) ? s[t - off] : 0;
        __syncthreads();
        s[t] += add;
        __syncthreads();
    }
    if (i < n) incl[i] = s[t];
    if (t == SCAN_BS - 1) partials[blockIdx.x] = s[t];
}
__global__ void scan_partials(int* __restrict__ partials, int nb) {  // 1 block, 512 thr
    __shared__ int s[512];
    int t = threadIdx.x;
    int v = (t < nb) ? partials[t] : 0;
    s[t] = v; __syncthreads();
    for (int off = 1; off < 512; off <<= 1) {
        int add = (t >= off) ? s[t - off] : 0;
        __syncthreads();
        s[t] += add;
        __syncthreads();
    }
    if (t < nb) partials[t] = s[t] - v;   // exclusive block offset
}
__global__ void finalize_rowptr(const int* __restrict__ deg, const int* __restrict__ incl,
                                const int* __restrict__ partials, int* __restrict__ row_ptr,
                                int* __restrict__ cursor, int n, int E) {
    int i = blockIdx.x * 256 + threadIdx.x;
    if (i < n) {
        int v = incl[i] - deg[i] + partials[i / SCAN_BS];
        row_ptr[i] = v;
        cursor[i] = v;
    } else if (i == n) {
        row_ptr[n] = E;
    }
}

// ------------------------------- MFMA GEMM ---------------------------------
// C tile (BM x BN) = A[M,(lda)] * Bt[.,K]^T (+bias, opt ELU). bf16 in, fp32 acc.
// BATCHZ: blockIdx.z = head; A col offset z*K, B ptr offset z*BN*K, C col offset z*BN.
// A/B frag [idx=lane&15][k=(lane>>4)*8+j]; C/D col=lane&15, row=(lane>>4)*4+reg.
template <int BM, int BN, int K, int WM, int WN, int MT, int NT,
          bool AF32, bool BIAS, bool OBF16, bool ELU, bool BATCHZ>
__launch_bounds__(256)
__global__ void gemm_mfma(const void* __restrict__ Ap, const unsigned short* __restrict__ Bt,
                          const float* __restrict__ bias, void* __restrict__ Cp, int M,
                          int lda, int ldc) {
    constexpr int LDK = 40;                    // pad 32 -> 40 shorts (80B rows, 16B-aligned)
    __shared__ unsigned short As[BM * LDK];
    __shared__ unsigned short Bs[BN * LDK];
    const int t = threadIdx.x;
    const long m0 = (long)blockIdx.x * BM;
    const long n0 = (long)blockIdx.y * BN;
    const int abase = BATCHZ ? blockIdx.z * K : 0;
    const unsigned short* Btz = BATCHZ ? Bt + (size_t)blockIdx.z * BN * K : Bt;
    const long cbase = BATCHZ ? (long)blockIdx.z * BN : 0;
    const int wave = t >> 6, lane = t & 63;
    const int wm = wave / WN, wn = wave % WN;
    const int lrow = lane & 15, lq = lane >> 4;

    f32x4 acc[MT][NT];
#pragma unroll
    for (int a = 0; a < MT; a++)
#pragma unroll
        for (int b = 0; b < NT; b++) acc[a][b] = (f32x4)0.0f;

    for (int kt = 0; kt < K / 32; kt++) {
        const int k0 = kt * 32;
        if constexpr (AF32) {
            const float* A = (const float*)Ap;
#pragma unroll
            for (int it = 0; it < BM * 8 / 256; it++) {
                int L = t + 256 * it;
                int row = L >> 3, kc = (L & 7) * 4;
                long gr = m0 + row;
                float4 v = make_float4(0.f, 0.f, 0.f, 0.f);
                if (gr < M) v = *(const float4*)&A[gr * lda + abase + k0 + kc];
                unsigned int lo = (unsigned)f2bf(v.x) | ((unsigned)f2bf(v.y) << 16);
                unsigned int hi = (unsigned)f2bf(v.z) | ((unsigned)f2bf(v.w) << 16);
                *(uint2*)&As[row * LDK + kc] = make_uint2(lo, hi);
            }
        } else {
            const unsigned short* A = (const unsigned short*)Ap;
#pragma unroll
            for (int it = 0; it < BM * 4 / 256; it++) {
                int L = t + 256 * it;
                int row = L >> 2, kc = (L & 3) * 8;
                long gr = m0 + row;
                uint4 v = make_uint4(0u, 0u, 0u, 0u);
                if (gr < M) v = *(const uint4*)&A[gr * lda + abase + k0 + kc];
                *(uint4*)&As[row * LDK + kc] = v;
            }
        }
#pragma unroll
        for (int it = 0; it < (BN * 4 + 255) / 256; it++) {
            int L = t + 256 * it;
            if (L < BN * 4) {
                int row = L >> 2, kc = (L & 3) * 8;
                *(uint4*)&Bs[row * LDK + kc] = *(const uint4*)&Btz[(n0 + row) * K + k0 + kc];
            }
        }
        __syncthreads();

        bf16x8 af[MT], bfr[NT];
#pragma unroll
        for (int mt = 0; mt < MT; mt++)
            af[mt] = *(const bf16x8*)&As[((wm * MT + mt) * 16 + lrow) * LDK + lq * 8];
#pragma unroll
        for (int nt = 0; nt < NT; nt++)
            bfr[nt] = *(const bf16x8*)&Bs[((wn * NT + nt) * 16 + lrow) * LDK + lq * 8];
#pragma unroll
        for (int mt = 0; mt < MT; mt++)
#pragma unroll
            for (int nt = 0; nt < NT; nt++)
                acc[mt][nt] = __builtin_amdgcn_mfma_f32_16x16x32_bf16(af[mt], bfr[nt],
                                                                     acc[mt][nt], 0, 0, 0);
        __syncthreads();
    }

#pragma unroll
    for (int mt = 0; mt < MT; mt++) {
        long rbase = m0 + (wm * MT + mt) * 16 + lq * 4;
#pragma unroll
        for (int nt = 0; nt < NT; nt++) {
            long col = cbase + n0 + (wn * NT + nt) * 16 + lrow;
            float bv = 0.f;
            if constexpr (BIAS) bv = bias[col];
#pragma unroll
            for (int r = 0; r < 4; r++) {
                long row = rbase + r;
                if (row < M) {
                    float v = acc[mt][nt][r] + bv;
                    if constexpr (ELU) v = v > 0.f ? v : __expf(v) - 1.0f;
                    if constexpr (OBF16)
                        ((unsigned short*)Cp)[row * ldc + col] = f2bf(v);
                    else
                        ((float*)Cp)[row * ldc + col] = v;
                }
            }
        }
    }
}

// ---------------- 8-head xp aggregation (chunked), zero shuffles -----------
// Wave per node. lane: head h=lane>>3, sub=lane&7 -> owns xp cols sub*16..+15.
// s16[i][0..7]=src scores, s16[i][8..15]=dst scores. 4-edge unroll (R7).
__global__ void agg_xp(const int* __restrict__ row_ptr, const int* __restrict__ dstp,
                       const float* __restrict__ s16,
                       const unsigned short* __restrict__ xp, unsigned short* __restrict__ z,
                       int n0, int n1) {
    int t = threadIdx.x, wave = t >> 6, lane = t & 63;
    int i = n0 + blockIdx.x * 4 + wave;
    if (i >= n1) return;
    int e0 = row_ptr[i], e1 = row_ptr[i + 1];
    int h = lane >> 3, sub = lane & 7;
    float ssv = s16[(size_t)i * 16 + h];
    float acc[16];
#pragma unroll
    for (int c = 0; c < 16; c++) acc[c] = 0.f;
    float rs = 0.f;
    int p = e0;
    for (; p + 4 <= e1; p += 4) {
        int j[4];
        float sc[4];
        uint4 xa[4], xb[4];
#pragma unroll
        for (int u = 0; u < 4; u++) j[u] = dstp[p + u];
#pragma unroll
        for (int u = 0; u < 4; u++) {
            sc[u] = ssv + s16[(size_t)j[u] * 16 + 8 + h];
            xa[u] = *(const uint4*)&xp[(size_t)j[u] * 128 + sub * 16];
            xb[u] = *(const uint4*)&xp[(size_t)j[u] * 128 + sub * 16 + 8];
        }
#pragma unroll
        for (int u = 0; u < 4; u++) {
            float s = sc[u];
            s = s > 0.f ? s : ALPHA_NEG * s;
            float w = __expf(-s);
            rs += w;
            unsigned ua[4] = {xa[u].x, xa[u].y, xa[u].z, xa[u].w};
            unsigned ub[4] = {xb[u].x, xb[u].y, xb[u].z, xb[u].w};
#pragma unroll
            for (int q = 0; q < 4; q++) {
                acc[2 * q]         += w * bflo(ua[q]);
                acc[2 * q + 1]     += w * bfhi(ua[q]);
                acc[8 + 2 * q]     += w * bflo(ub[q]);
                acc[8 + 2 * q + 1] += w * bfhi(ub[q]);
            }
        }
    }
    for (; p < e1; p++) {
        int j0 = dstp[p];
        float s0 = ssv + s16[(size_t)j0 * 16 + 8 + h];
        uint4 xa0 = *(const uint4*)&xp[(size_t)j0 * 128 + sub * 16];
        uint4 xb0 = *(const uint4*)&xp[(size_t)j0 * 128 + sub * 16 + 8];
        s0 = s0 > 0.f ? s0 : ALPHA_NEG * s0;
        float w0 = __expf(-s0);
        rs += w0;
        unsigned ua0[4] = {xa0.x, xa0.y, xa0.z, xa0.w};
        unsigned ub0[4] = {xb0.x, xb0.y, xb0.z, xb0.w};
#pragma unroll
        for (int q = 0; q < 4; q++) {
            acc[2 * q]         += w0 * bflo(ua0[q]);
            acc[2 * q + 1]     += w0 * bfhi(ua0[q]);
            acc[8 + 2 * q]     += w0 * bflo(ub0[q]);
            acc[8 + 2 * q + 1] += w0 * bfhi(ub0[q]);
        }
    }
    float inv = 1.0f / (rs + 1e-16f);
    uint4 o0, o1;
    unsigned* po0 = (unsigned*)&o0;
    unsigned* po1 = (unsigned*)&o1;
#pragma unroll
    for (int q = 0; q < 4; q++) {
        po0[q] = (unsigned)f2bf(acc[2 * q] * inv) | ((unsigned)f2bf(acc[2 * q + 1] * inv) << 16);
        po1[q] = (unsigned)f2bf(acc[8 + 2 * q] * inv) | ((unsigned)f2bf(acc[8 + 2 * q + 1] * inv) << 16);
    }
    size_t zb = (size_t)(i - n0) * 1024 + h * 128 + sub * 16;
    *(uint4*)&z[zb] = o0;
    *(uint4*)&z[zb + 8] = o1;
}

// ----------------------------- final-layer scores --------------------------
__global__ void scores2(const unsigned short* __restrict__ h2b, const float* __restrict__ ae,
                        float* __restrict__ ss2, float* __restrict__ sd2, int n) {
    int t = threadIdx.x, wave = t >> 6, lane = t & 63;
    int i = blockIdx.x * 4 + wave;
    if (i >= n) return;
    float v = bfs(h2b[(size_t)i * 64 + lane]);
    float a = v * ae[lane];
    float b = v * ae[64 + lane];
    for (int d = 32; d > 0; d >>= 1) {
        a += __shfl_xor(a, d, 64);
        b += __shfl_xor(b, d, 64);
    }
    if (lane == 0) { ss2[i] = a; sd2[i] = b; }
}

// --------------------- final aggregation + row softmax ---------------------
// Wave per node, lane = col; bf16 h2 gather (128 B/edge), 4-way unroll.
__global__ void agg_final(const int* __restrict__ row_ptr, const int* __restrict__ dstp,
                          const float* __restrict__ ss2, const float* __restrict__ sd2,
                          const unsigned short* __restrict__ h2b, float* __restrict__ out,
                          int n) {
    int t = threadIdx.x, wave = t >> 6, lane = t & 63;
    int i = blockIdx.x * 4 + wave;
    if (i >= n) return;
    int e0 = row_ptr[i], e1 = row_ptr[i + 1];
    float ssrc = ss2[i];
    float acc = 0.f, rs = 0.f;
    int p = e0;
    for (; p + 4 <= e1; p += 4) {
        int j0 = dstp[p], j1 = dstp[p + 1], j2 = dstp[p + 2], j3 = dstp[p + 3];
        float s0 = ssrc + sd2[j0], s1 = ssrc + sd2[j1];
        float s2 = ssrc + sd2[j2], s3 = ssrc + sd2[j3];
        float v0 = bfs(h2b[(size_t)j0 * 64 + lane]), v1 = bfs(h2b[(size_t)j1 * 64 + lane]);
        float v2 = bfs(h2b[(size_t)j2 * 64 + lane]), v3 = bfs(h2b[(size_t)j3 * 64 + lane]);
        s0 = s0 > 0.f ? s0 : ALPHA_NEG * s0;
        s1 = s1 > 0.f ? s1 : ALPHA_NEG * s1;
        s2 = s2 > 0.f ? s2 : ALPHA_NEG * s2;
        s3 = s3 > 0.f ? s3 : ALPHA_NEG * s3;
        float w0 = __expf(-s0), w1 = __expf(-s1), w2 = __expf(-s2), w3 = __expf(-s3);
        rs += (w0 + w1) + (w2 + w3);
        acc += w0 * v0 + w1 * v1 + w2 * v2 + w3 * v3;
    }
    for (; p < e1; p++) {
        int j = dstp[p];
        float sc = ssrc + sd2[j];
        sc = sc > 0.f ? sc : ALPHA_NEG * sc;
        float w = __expf(-sc);
        acc += w * bfs(h2b[(size_t)j * 64 + lane]);
        rs += w;
    }
    float o = acc / (rs + 1e-16f);
    float m = o;
    for (int d = 32; d > 0; d >>= 1) m = fmaxf(m, __shfl_xor(m, d, 64));
    float e = __expf(o - m);
    float s = e;
    for (int d = 32; d > 0; d >>= 1) s += __shfl_xor(s, d, 64);
    out[(size_t)i * 64 + lane] = e / s;
}

// ------------------------------- launcher ----------------------------------
extern "C" void kernel_launch(void* const* d_in, const int* in_sizes, int n_in,
                              void* d_out, int out_size, void* d_ws, size_t ws_size,
                              hipStream_t stream) {
    const float* x  = (const float*)d_in[0];
    const int* edges = (const int*)d_in[1];
    const float* W0 = (const float*)d_in[2];
    const float* b0 = (const float*)d_in[3];
    const float* Wh = (const float*)d_in[4];
    const float* ah = (const float*)d_in[5];
    const float* We = (const float*)d_in[6];
    const float* ae = (const float*)d_in[7];
    float* dout = (float*)d_out;

    const int Nn = in_sizes[0] / 128;   // 100000
    const int E  = in_sizes[1] / 2;     // 1600000
    const int* src = edges;
    const int* dst = edges + E;
    const int npo = (Nn + 7) / 8;       // nodes per XCD owner

    char* p = (char*)d_ws;
    auto alloc = [&](size_t bytes) -> char* {
        char* r = p;
        p += (bytes + 255) & ~(size_t)255;
        return r;
    };
    unsigned short* W0t   = (unsigned short*)alloc(128 * 128 * 2);
    unsigned short* Ballt = (unsigned short*)alloc(512 * 128 * 2);
    unsigned short* Wendt = (unsigned short*)alloc((size_t)64 * 512 * 2);
    unsigned short* Bscore = (unsigned short*)alloc(16 * 128 * 2);
    int* deg     = (int*)alloc((size_t)Nn * 4);
    int* incl    = (int*)alloc((size_t)Nn * 4);
    int* part    = (int*)alloc(512 * 4);
    int* row_ptr = (int*)alloc((size_t)(Nn + 1) * 4);
    int* cursor  = (int*)alloc((size_t)Nn * 4);
    int* dstp    = (int*)alloc((size_t)E * 4);
    float* s16   = (float*)alloc((size_t)Nn * 16 * 4);
    float* ss2   = (float*)alloc((size_t)Nn * 4);
    float* sd2   = (float*)alloc((size_t)Nn * 4);
    unsigned short* xp = (unsigned short*)alloc((size_t)Nn * 128 * 2);
    unsigned short* z  = (unsigned short*)alloc((size_t)CHUNK * 1024 * 2); // h2b aliases
    unsigned short* hcat = (unsigned short*)alloc((size_t)Nn * 512 * 2);
    unsigned short* h2b = (unsigned short*)z;   // [N,64] bf16 = 12.8 MB << z

    size_t needed = (size_t)(p - (char*)d_ws);
    if (needed > ws_size) return;       // diagnostic guard

    const int gm = (Nn + 127) / 128;
    const int nScanB = (Nn + SCAN_BS - 1) / SCAN_BS;
    const int eb = (E + 255) / 256;     // edge chunks

    hipMemsetAsync(deg, 0, (size_t)Nn * 4, stream);
    pack_w0<<<64, 256, 0, stream>>>(W0, W0t);
    pack_ball<<<256, 256, 0, stream>>>(Wh, Ballt);
    pack_wend<<<128, 256, 0, stream>>>(We, Wendt);
    pack_wa<<<4, 256, 0, stream>>>(Wh, ah, Bscore);

    edge_hist_own<<<eb * 8, 256, 0, stream>>>(src, deg, E, npo);
    scan_blocks<<<nScanB, 256, 0, stream>>>(deg, incl, part, Nn);
    scan_partials<<<1, 512, 0, stream>>>(part, nScanB);
    finalize_rowptr<<<(Nn + 256) / 256, 256, 0, stream>>>(deg, incl, part, row_ptr, cursor, Nn, E);
    edge_scatter_own<<<eb * 8, 256, 0, stream>>>(src, dst, cursor, dstp, E, npo);

    // xp = bf16(x @ W0 + b0)
    gemm_mfma<128, 128, 128, 2, 2, 4, 4, true, true, true, false, false>
        <<<dim3(gm, 1), 256, 0, stream>>>(x, W0t, b0, xp, Nn, 128, 128);

    // s16[N,16] = xp @ Bscore^T  (cols 0..7 = src scores, 8..15 = dst scores)
    gemm_mfma<128, 16, 128, 4, 1, 2, 1, false, false, false, false, false>
        <<<dim3(gm, 1), 256, 0, stream>>>(xp, Bscore, nullptr, s16, Nn, 128, 16);

    // chunked: z = normalized xp-aggregation; hcat = ELU(z_h @ W_h) per head
    for (int c0 = 0; c0 < Nn; c0 += CHUNK) {
        int c1 = min(c0 + CHUNK, Nn);
        int Mc = c1 - c0;
        agg_xp<<<(Mc + 3) / 4, 256, 0, stream>>>(row_ptr, dstp, s16, xp, z, c0, c1);
        gemm_mfma<128, 64, 128, 4, 1, 2, 4, false, false, true, true, true>
            <<<dim3((Mc + 127) / 128, 1, 8), 256, 0, stream>>>(
                z, Ballt, nullptr, hcat + (size_t)c0 * 512, Mc, 1024, 512);
    }

    // h2b = bf16(hcat @ W_end)  [N,64]   (aliases z, now dead)
    gemm_mfma<128, 64, 512, 4, 1, 2, 4, false, false, true, false, false>
        <<<dim3(gm, 1), 256, 0, stream>>>(hcat, Wendt, nullptr, h2b, Nn, 512, 64);

    scores2<<<(Nn + 3) / 4, 256, 0, stream>>>(h2b, ae, ss2, sd2, Nn);
    agg_final<<<(Nn + 3) / 4, 256, 0, stream>>>(row_ptr, dstp, ss2, sd2, h2b, dout, Nn);
}